// Round 13
// baseline (510.430 us; speedup 1.0000x reference)
//
#include <hip/hip_runtime.h>
#include <hip/hip_bf16.h>
#include <stdint.h>

// ---------- types ----------
typedef __attribute__((ext_vector_type(8))) short     short8;   // 8 bf16 (raw bits)
typedef __attribute__((ext_vector_type(8))) _Float16  f16x8;    // 8 fp16
typedef __attribute__((ext_vector_type(4))) float     f32x4;
typedef __attribute__((ext_vector_type(8))) unsigned short ushort8;
typedef __attribute__((ext_vector_type(4))) unsigned short ushort4_t;

// ---------- scalar conversion helpers ----------
__device__ inline unsigned short f2bf(float f) {
    unsigned u = __float_as_uint(f);
    u += 0x7fffu + ((u >> 16) & 1u);          // RNE
    return (unsigned short)(u >> 16);
}
__device__ inline float bf2f(unsigned short h) {
    return __uint_as_float(((unsigned)h) << 16);
}
__device__ inline unsigned short f2h(float f) {
    _Float16 h = (_Float16)f;
    unsigned short r;
    __builtin_memcpy(&r, &h, 2);
    return r;
}

// ---------- async global->LDS (width 16) ----------
__device__ inline void gload16(const void* g, void* lds) {
    unsigned loff = (unsigned)(uintptr_t)lds;
    loff = __builtin_amdgcn_readfirstlane(loff);
    auto l = (__attribute__((address_space(3))) unsigned int*)(uintptr_t)loff;
    auto p = (const __attribute__((address_space(1))) unsigned int*)(uintptr_t)g;
    __builtin_amdgcn_global_load_lds(p, l, 16, 0, 0);
}

// =====================================================================
// Batched elementwise f32 -> 2-byte: y=0 key->f16, y=1 query->f16, y=2 value->bf16
// =====================================================================
__global__ void cvt3_f32_2b(const float4* __restrict__ k, const float4* __restrict__ q,
                            const float4* __restrict__ v,
                            ushort4_t* __restrict__ k16, ushort4_t* __restrict__ q16,
                            ushort4_t* __restrict__ v16, int n4) {
    const int which = blockIdx.y;
    const float4* in  = which == 0 ? k   : which == 1 ? q   : v;
    ushort4_t*    out = which == 0 ? k16 : which == 1 ? q16 : v16;
    const bool tof16 = (which < 2);
    for (int i = blockIdx.x * blockDim.x + threadIdx.x; i < n4; i += gridDim.x * blockDim.x) {
        float4 vv = in[i];
        ushort4_t r;
        if (tof16) { r.x = f2h(vv.x);  r.y = f2h(vv.y);  r.z = f2h(vv.z);  r.w = f2h(vv.w); }
        else       { r.x = f2bf(vv.x); r.y = f2bf(vv.y); r.z = f2bf(vv.z); r.w = f2bf(vv.w); }
        out[i] = r;
    }
}

// =====================================================================
// Weight transpose + convert: W[dim][dim] f32 -> WT[n][k] 2-byte
// =====================================================================
template<int TOF16>
__global__ void transpose_cvt(const float* __restrict__ W, unsigned short* __restrict__ WT, int dim) {
    __shared__ float t[32][33];
    const int bx = blockIdx.x * 32, by = blockIdx.y * 32;   // bx: n, by: k
    const int tx = threadIdx.x, ty = threadIdx.y;
#pragma unroll
    for (int i = 0; i < 4; ++i)
        t[ty + 8 * i][tx] = W[(size_t)(by + ty + 8 * i) * dim + bx + tx];
    __syncthreads();
#pragma unroll
    for (int i = 0; i < 4; ++i) {
        float v = t[tx][ty + 8 * i];
        WT[(size_t)(bx + ty + 8 * i) * dim + by + tx] = TOF16 ? f2h(v) : f2bf(v);
    }
}

// =====================================================================
// v [128][1024][64] bf16 -> vT [128][64][1024] bf16
// =====================================================================
__global__ void transpose_v(const unsigned short* __restrict__ v, unsigned short* __restrict__ vT) {
    const int bh = blockIdx.z, d0 = blockIdx.x * 32, s0 = blockIdx.y * 32;
    __shared__ unsigned short t[32][33];
    const int tx = threadIdx.x, ty = threadIdx.y;
    const size_t base = (size_t)bh << 16;
#pragma unroll
    for (int i = 0; i < 4; ++i)
        t[ty + 8 * i][tx] = v[base + (size_t)(s0 + ty + 8 * i) * 64 + d0 + tx];
    __syncthreads();
#pragma unroll
    for (int i = 0; i < 4; ++i)
        vT[base + (size_t)(d0 + ty + 8 * i) * 1024 + s0 + tx] = t[tx][ty + 8 * i];
}

// =====================================================================
// GEMM (B^T form), 2-phase double-buffered (T3 minimum), as in round 8:
//   stage(k+1) -> s_waitcnt vmcnt(4) -> raw s_barrier -> MFMA(k) -> s_barrier.
// =====================================================================
template<int F16IN, int EPI>
__global__ __launch_bounds__(256, 2) void gemm_bt(
    const unsigned short* __restrict__ A,
    const unsigned short* __restrict__ Bt,
    const float* __restrict__ bias,
    unsigned short* __restrict__ C2b,
    const float* __restrict__ resid,
    float* __restrict__ Cf,
    int M, int N, int K, int nbx)
{
    const int bid = blockIdx.x;
    const int cpx = gridDim.x >> 3;
    const int swz = (bid & 7) * cpx + (bid >> 3);
    const int bm = swz / nbx, bn = swz % nbx;
    const int m0 = bm * 128, n0 = bn * 128;

    const int tid = threadIdx.x;
    const int w = tid >> 6, l = tid & 63, g = l >> 4, c = l & 15;
    const int wr = w >> 1, wc = w & 1;

    __shared__ unsigned short As[2][4096];   // 2 x [128][32]
    __shared__ unsigned short Bs[2][4096];

    f32x4 acc[4][4] = {};

    const int arow = tid >> 2, acol = (tid & 3) * 8;
    const unsigned short* Ap  = A  + (size_t)(m0 + arow) * K + acol;
    const unsigned short* Ap2 = A  + (size_t)(m0 + 64 + arow) * K + acol;
    const unsigned short* Bp  = Bt + (size_t)(n0 + arow) * K + acol;
    const unsigned short* Bp2 = Bt + (size_t)(n0 + 64 + arow) * K + acol;

    const int NT = K >> 5;

#define STAGE_GEMM(bufi, koff)                                   \
    do {                                                         \
        gload16(Ap  + (koff), &As[bufi][w * 512]);               \
        gload16(Ap2 + (koff), &As[bufi][2048 + w * 512]);        \
        gload16(Bp  + (koff), &Bs[bufi][w * 512]);               \
        gload16(Bp2 + (koff), &Bs[bufi][2048 + w * 512]);        \
    } while (0)

#define COMPUTE_GEMM(bufi)                                                         \
    do {                                                                           \
        if constexpr (F16IN) {                                                     \
            f16x8 a[4], b[4];                                                      \
            _Pragma("unroll")                                                      \
            for (int mt = 0; mt < 4; ++mt)                                         \
                a[mt] = *(const f16x8*)&As[bufi][(wr * 64 + mt * 16 + c) * 32 + g * 8]; \
            _Pragma("unroll")                                                      \
            for (int nt = 0; nt < 4; ++nt)                                         \
                b[nt] = *(const f16x8*)&Bs[bufi][(wc * 64 + nt * 16 + c) * 32 + g * 8]; \
            _Pragma("unroll")                                                      \
            for (int mt = 0; mt < 4; ++mt)                                         \
                _Pragma("unroll")                                                  \
                for (int nt = 0; nt < 4; ++nt)                                     \
                    acc[mt][nt] = __builtin_amdgcn_mfma_f32_16x16x32_f16(a[mt], b[nt], acc[mt][nt], 0, 0, 0); \
        } else {                                                                   \
            short8 a[4], b[4];                                                     \
            _Pragma("unroll")                                                      \
            for (int mt = 0; mt < 4; ++mt)                                         \
                a[mt] = *(const short8*)&As[bufi][(wr * 64 + mt * 16 + c) * 32 + g * 8]; \
            _Pragma("unroll")                                                      \
            for (int nt = 0; nt < 4; ++nt)                                         \
                b[nt] = *(const short8*)&Bs[bufi][(wc * 64 + nt * 16 + c) * 32 + g * 8]; \
            _Pragma("unroll")                                                      \
            for (int mt = 0; mt < 4; ++mt)                                         \
                _Pragma("unroll")                                                  \
                for (int nt = 0; nt < 4; ++nt)                                     \
                    acc[mt][nt] = __builtin_amdgcn_mfma_f32_16x16x32_bf16(a[mt], b[nt], acc[mt][nt], 0, 0, 0); \
        }                                                                          \
    } while (0)

    STAGE_GEMM(0, 0);

#pragma unroll 2
    for (int kt = 0; kt < NT - 1; ++kt) {
        const int cur = kt & 1;
        STAGE_GEMM(cur ^ 1, (kt + 1) * 32);
        asm volatile("s_waitcnt vmcnt(4)" ::: "memory");
        __builtin_amdgcn_s_barrier();
        __builtin_amdgcn_sched_barrier(0);
        COMPUTE_GEMM(cur);
        __builtin_amdgcn_sched_barrier(0);
        __builtin_amdgcn_s_barrier();
    }
    asm volatile("s_waitcnt vmcnt(0)" ::: "memory");
    __builtin_amdgcn_s_barrier();
    __builtin_amdgcn_sched_barrier(0);
    COMPUTE_GEMM((NT - 1) & 1);

#undef STAGE_GEMM
#undef COMPUTE_GEMM

#pragma unroll
    for (int nt = 0; nt < 4; ++nt) {
        const int col = n0 + wc * 64 + nt * 16 + c;
        const float bs = bias[col];
#pragma unroll
        for (int mt = 0; mt < 4; ++mt) {
            const int row0 = m0 + wr * 64 + mt * 16 + g * 4;
#pragma unroll
            for (int r = 0; r < 4; ++r) {
                const float x = acc[mt][nt][r] + bs;
                const size_t idx = (size_t)(row0 + r) * N + col;
                if constexpr (EPI == 0) {
                    C2b[idx] = F16IN ? f2h(x) : f2bf(x);
                } else {
                    Cf[idx] = x + resid[idx];
                }
            }
        }
    }
}

// =====================================================================
// Attention v10 = r8 (v6) EXACTLY, except attention stores are PLAIN
// (cached) instead of nontemporal: consecutive t-iterations write
// adjacent 64B sectors of the same row -> L2 write-back merges them
// into full 128B lines before eviction (NT bypassed that merge and
// amplified HBM writes ~2x: r10 983MB / r9 1954MB vs v1's clean 545MB).
//  - swapped QK^T; packed bf16 pks[16]; PV loop with interleaved stores;
//    XCD-chunked decode. One block = (bh, 16 q-rows); grid = 8192.
// =====================================================================
__global__ __launch_bounds__(256, 4) void attn_kernel(
    const unsigned short* __restrict__ qf,   // f16  [128*1024*64]
    const unsigned short* __restrict__ kf,   // f16  [128*1024*64]
    const unsigned short* __restrict__ vT,   // bf16 [128][64][1024]
    float* __restrict__ attn_out,            // f32  [128][1024][1024]
    unsigned short* __restrict__ ctx)        // bf16 [128*1024*64]
{
    const int L = blockIdx.x;
    const int rb = (L >> 3) & 63;
    const int bh = ((L & 7) << 4) | (L >> 9);

    const int tid = threadIdx.x;
    const int w = tid >> 6, l = tid & 63, g = l >> 4, c = l & 15;
    const int n0 = w * 256;

    __shared__ unsigned short P[16 * 1024];  // 32 KB, XOR-swizzled by (row&7)<<4
    __shared__ float rs_lds[4][16];
    __shared__ float inv_lds[16];

    // Q fragment (B-operand): lane holds Q[row = rb*16 + c][d = g*8 .. +7] (+32)
    const unsigned short* qb = qf + ((size_t)bh << 16) + (size_t)(rb * 16 + c) * 64 + g * 8;
    const f16x8 q0 = *(const f16x8*)(qb);
    const f16x8 q1 = *(const f16x8*)(qb + 32);

    const unsigned short* kb = kf + ((size_t)bh << 16);
    const unsigned swzc = ((unsigned)(c & 7)) << 4;
    const unsigned prow = (unsigned)c * 2048;

    ushort4_t pks[16];
    float rsum = 0.f;

    // QK^T: per t, A-operand = K rows (= attention cols) n0+t*16+c, d-chunk g*8.
    // Output: lane holds score[q = c][kcol = n0 + t*16 + g*4 + r].
#pragma unroll
    for (int t = 0; t < 16; ++t) {
        const unsigned short* kp = kb + (size_t)(n0 + t * 16 + c) * 64 + g * 8;
        const f16x8 a0 = *(const f16x8*)(kp);
        const f16x8 a1 = *(const f16x8*)(kp + 32);
        f32x4 s = {0.f, 0.f, 0.f, 0.f};
        s = __builtin_amdgcn_mfma_f32_16x16x32_f16(a0, q0, s, 0, 0, 0);
        s = __builtin_amdgcn_mfma_f32_16x16x32_f16(a1, q1, s, 0, 0, 0);

        const float p0 = __expf(s[0] * 0.5f);
        const float p1 = __expf(s[1] * 0.5f);
        const float p2 = __expf(s[2] * 0.5f);
        const float p3 = __expf(s[3] * 0.5f);
        rsum += (p0 + p1) + (p2 + p3);

        ushort4_t pk;
        pk.x = f2bf(p0); pk.y = f2bf(p1); pk.z = f2bf(p2); pk.w = f2bf(p3);
        pks[t] = pk;
        *(ushort4_t*)((char*)P + ((prow + (unsigned)(n0 * 2 + t * 32 + g * 8)) ^ swzc)) = pk;
    }

    // row-sum for row c: reduce over the 4 lane-groups (lane-id bits 4,5)
    rsum += __shfl_xor(rsum, 16);
    rsum += __shfl_xor(rsum, 32);
    if (g == 0) rs_lds[w][c] = rsum;
    __syncthreads();                          // also covers P ds_writes
    if (tid < 16)
        inv_lds[tid] = 1.0f / (rs_lds[0][tid] + rs_lds[1][tid] + rs_lds[2][tid] + rs_lds[3][tid]);
    __syncthreads();

    // PV with interleaved attention stores (PLAIN stores -> L2 merges
    // adjacent 64B sectors across t into full lines).
    const float inv = inv_lds[c];
    float* ao = attn_out + ((size_t)bh << 20) + (size_t)(rb * 16 + c) * 1024 + n0 + g * 4;
    f32x4 pacc = {0.f, 0.f, 0.f, 0.f};
    const unsigned short* vb = vT + ((size_t)bh << 16) + (size_t)(w * 16 + c) * 1024;
#pragma unroll
    for (int ks = 0; ks < 32; ++ks) {
        const short8 a = *(const short8*)((char*)P + ((prow + (unsigned)(ks * 64 + g * 16)) ^ swzc));
        const short8 b = *(const short8*)(vb + ks * 32 + g * 8);
        pacc = __builtin_amdgcn_mfma_f32_16x16x32_bf16(a, b, pacc, 0, 0, 0);
        if (ks & 1) {
            const int t = ks >> 1;
            const ushort4_t pk = pks[t];
            f32x4 o;
            o[0] = bf2f(pk.x) * inv;
            o[1] = bf2f(pk.y) * inv;
            o[2] = bf2f(pk.z) * inv;
            o[3] = bf2f(pk.w) * inv;
            *(f32x4*)(ao + t * 16) = o;
        }
    }
    unsigned short* cb = ctx + ((size_t)bh << 16) + (size_t)(rb * 16) * 64 + w * 16 + c;
#pragma unroll
    for (int r = 0; r < 4; ++r) {
        const int row = g * 4 + r;
        cb[(size_t)row * 64] = f2bf(pacc[r] * inv_lds[row]);
    }
}

// =====================================================================
// BatchNorm over channels (deterministic two-level reduction)
// =====================================================================
__global__ void bn_stats(const float* __restrict__ x, float* __restrict__ psum, float* __restrict__ psq) {
    const int col = blockIdx.y * 256 + threadIdx.x;   // grid.y = 4
    const int r0 = blockIdx.x * 128;                  // grid.x = 64
    float s = 0.f, q = 0.f;
#pragma unroll 4
    for (int r = 0; r < 128; ++r) {
        const float v = x[(size_t)(r0 + r) * 1024 + col];
        s += v; q += v * v;
    }
    psum[blockIdx.x * 1024 + col] = s;
    psq [blockIdx.x * 1024 + col] = q;
}

__global__ void bn_final(const float* __restrict__ psum, const float* __restrict__ psq,
                         const float* __restrict__ gamma, const float* __restrict__ beta,
                         float* __restrict__ ab) {
    const int cidx = threadIdx.x;   // 1024 threads
    float s = 0.f, q = 0.f;
#pragma unroll 8
    for (int i = 0; i < 64; ++i) { s += psum[i * 1024 + cidx]; q += psq[i * 1024 + cidx]; }
    const float mean = s * (1.0f / 8192.0f);
    const float var  = q * (1.0f / 8192.0f) - mean * mean;
    const float a = gamma[cidx] * rsqrtf(var + 1e-5f);
    ab[cidx]        = a;
    ab[1024 + cidx] = beta[cidx] - mean * a;
}

__global__ void bn_apply(const float4* __restrict__ x4, const float* __restrict__ ab, float4* __restrict__ o4) {
    const int n4 = 2 * 1024 * 1024;
    for (int i = blockIdx.x * blockDim.x + threadIdx.x; i < n4; i += gridDim.x * blockDim.x) {
        const float4 v = x4[i];
        const int c0 = (i & 255) << 2;
        float4 r;
        r.x = v.x * ab[c0 + 0] + ab[1024 + c0 + 0];
        r.y = v.y * ab[c0 + 1] + ab[1024 + c0 + 1];
        r.z = v.z * ab[c0 + 2] + ab[1024 + c0 + 2];
        r.w = v.w * ab[c0 + 3] + ab[1024 + c0 + 3];
        o4[i] = r;
    }
}

// =====================================================================
// launch
// =====================================================================
extern "C" void kernel_launch(void* const* d_in, const int* in_sizes, int n_in,
                              void* d_out, int out_size, void* d_ws, size_t ws_size,
                              hipStream_t stream) {
    (void)in_sizes; (void)n_in; (void)out_size; (void)ws_size;

    const float* key   = (const float*)d_in[0];
    const float* value = (const float*)d_in[1];
    const float* query = (const float*)d_in[2];
    const float* Wk = (const float*)d_in[3];
    const float* bk = (const float*)d_in[4];
    const float* Wv = (const float*)d_in[5];
    const float* bv = (const float*)d_in[6];
    const float* Wq = (const float*)d_in[7];
    const float* bq = (const float*)d_in[8];
    const float* Wf = (const float*)d_in[9];
    const float* bff = (const float*)d_in[10];
    const float* gamma = (const float*)d_in[11];
    const float* beta  = (const float*)d_in[12];

    char* ws = (char*)d_ws;
    const size_t MB = 1u << 20;
    unsigned short* key16   = (unsigned short*)(ws + 0);        // dead after GEMM-k -> ctx
    unsigned short* ctx     = (unsigned short*)(ws + 0);
    unsigned short* query16 = (unsigned short*)(ws + 16 * MB);
    unsigned short* value16 = (unsigned short*)(ws + 32 * MB);
    float*          xbuf    = (float*)(ws + 16 * MB);           // 32 MB
    unsigned short* WkT = (unsigned short*)(ws + 48 * MB);
    unsigned short* WqT = (unsigned short*)(ws + 50 * MB);
    unsigned short* WvT = (unsigned short*)(ws + 52 * MB);
    unsigned short* WfT = (unsigned short*)(ws + 54 * MB);
    unsigned short* kbuf = (unsigned short*)(ws + 56 * MB);
    unsigned short* qbuf = (unsigned short*)(ws + 72 * MB);
    unsigned short* vbuf = (unsigned short*)(ws + 88 * MB);
    float* psum = (float*)(ws + 88 * MB);
    float* psq  = (float*)(ws + 88 * MB + 256 * 1024);
    float* ab   = (float*)(ws + 88 * MB + 512 * 1024);
    unsigned short* vTbuf = (unsigned short*)(ws + 104 * MB);

    float* out0 = (float*)d_out;            // [8M]  normalized output
    float* attn = out0 + 8388608;           // [128M] attention

    const int n4big = 2 * 1024 * 1024;

    // 1) input conversions (single batched launch)
    cvt3_f32_2b<<<dim3(1024, 3), 256, 0, stream>>>(
        (const float4*)key, (const float4*)query, (const float4*)value,
        (ushort4_t*)key16, (ushort4_t*)query16, (ushort4_t*)value16, n4big);

    // 2) weight transposes
    dim3 tb(32, 8), tg(32, 32);
    transpose_cvt<1><<<tg, tb, 0, stream>>>(Wk, WkT, 1024);
    transpose_cvt<1><<<tg, tb, 0, stream>>>(Wq, WqT, 1024);
    transpose_cvt<0><<<tg, tb, 0, stream>>>(Wv, WvT, 1024);
    transpose_cvt<0><<<tg, tb, 0, stream>>>(Wf, WfT, 1024);

    // 3) QKV projections (M=8192, N=1024, K=1024), f16 for q/k, bf16 for v
    gemm_bt<1, 0><<<512, 256, 0, stream>>>(key16,   WkT, bk, kbuf, nullptr, nullptr, 8192, 1024, 1024, 8);
    gemm_bt<1, 0><<<512, 256, 0, stream>>>(query16, WqT, bq, qbuf, nullptr, nullptr, 8192, 1024, 1024, 8);
    gemm_bt<0, 0><<<512, 256, 0, stream>>>(value16, WvT, bv, vbuf, nullptr, nullptr, 8192, 1024, 1024, 8);

    // 4) v -> vT per head-batch
    transpose_v<<<dim3(2, 32, 128), tb, 0, stream>>>(vbuf, vTbuf);

    // 5) attention (writes attention matrix + ctx), XCD-chunked 1-D grid
    attn_kernel<<<8192, 256, 0, stream>>>(qbuf, kbuf, vTbuf, attn, ctx);

    // 6) output projection + residual -> xbuf (f32)
    gemm_bt<0, 1><<<512, 256, 0, stream>>>(ctx, WfT, bff, nullptr, query, xbuf, 8192, 1024, 1024, 8);

    // 7) BatchNorm (deterministic)
    bn_stats<<<dim3(64, 4), 256, 0, stream>>>(xbuf, psum, psq);
    bn_final<<<1, 1024, 0, stream>>>(psum, psq, gamma, beta, ab);
    bn_apply<<<2048, 256, 0, stream>>>((const float4*)xbuf, ab, (float4*)out0);
}

// Round 14
// 461.317 us; speedup vs baseline: 1.1065x; 1.1065x over previous
//
#include <hip/hip_runtime.h>
#include <hip/hip_bf16.h>
#include <stdint.h>

// ---------- types ----------
typedef __attribute__((ext_vector_type(8))) short     short8;   // 8 bf16 (raw bits)
typedef __attribute__((ext_vector_type(8))) _Float16  f16x8;    // 8 fp16
typedef __attribute__((ext_vector_type(4))) float     f32x4;
typedef __attribute__((ext_vector_type(8))) unsigned short ushort8;
typedef __attribute__((ext_vector_type(4))) unsigned short ushort4_t;

// ---------- scalar conversion helpers ----------
__device__ inline unsigned short f2bf(float f) {
    unsigned u = __float_as_uint(f);
    u += 0x7fffu + ((u >> 16) & 1u);          // RNE
    return (unsigned short)(u >> 16);
}
__device__ inline float bf2f(unsigned short h) {
    return __uint_as_float(((unsigned)h) << 16);
}
__device__ inline unsigned short f2h(float f) {
    _Float16 h = (_Float16)f;
    unsigned short r;
    __builtin_memcpy(&r, &h, 2);
    return r;
}

// ---------- async global->LDS (width 16) ----------
__device__ inline void gload16(const void* g, void* lds) {
    unsigned loff = (unsigned)(uintptr_t)lds;
    loff = __builtin_amdgcn_readfirstlane(loff);
    auto l = (__attribute__((address_space(3))) unsigned int*)(uintptr_t)loff;
    auto p = (const __attribute__((address_space(1))) unsigned int*)(uintptr_t)g;
    __builtin_amdgcn_global_load_lds(p, l, 16, 0, 0);
}

// =====================================================================
// Batched elementwise f32 -> 2-byte: y=0 key->f16, y=1 query->f16, y=2 value->bf16
// =====================================================================
__global__ void cvt3_f32_2b(const float4* __restrict__ k, const float4* __restrict__ q,
                            const float4* __restrict__ v,
                            ushort4_t* __restrict__ k16, ushort4_t* __restrict__ q16,
                            ushort4_t* __restrict__ v16, int n4) {
    const int which = blockIdx.y;
    const float4* in  = which == 0 ? k   : which == 1 ? q   : v;
    ushort4_t*    out = which == 0 ? k16 : which == 1 ? q16 : v16;
    const bool tof16 = (which < 2);
    for (int i = blockIdx.x * blockDim.x + threadIdx.x; i < n4; i += gridDim.x * blockDim.x) {
        float4 vv = in[i];
        ushort4_t r;
        if (tof16) { r.x = f2h(vv.x);  r.y = f2h(vv.y);  r.z = f2h(vv.z);  r.w = f2h(vv.w); }
        else       { r.x = f2bf(vv.x); r.y = f2bf(vv.y); r.z = f2bf(vv.z); r.w = f2bf(vv.w); }
        out[i] = r;
    }
}

// =====================================================================
// Weight transpose + convert: W[dim][dim] f32 -> WT[n][k] 2-byte
// =====================================================================
template<int TOF16>
__global__ void transpose_cvt(const float* __restrict__ W, unsigned short* __restrict__ WT, int dim) {
    __shared__ float t[32][33];
    const int bx = blockIdx.x * 32, by = blockIdx.y * 32;   // bx: n, by: k
    const int tx = threadIdx.x, ty = threadIdx.y;
#pragma unroll
    for (int i = 0; i < 4; ++i)
        t[ty + 8 * i][tx] = W[(size_t)(by + ty + 8 * i) * dim + bx + tx];
    __syncthreads();
#pragma unroll
    for (int i = 0; i < 4; ++i) {
        float v = t[tx][ty + 8 * i];
        WT[(size_t)(bx + ty + 8 * i) * dim + by + tx] = TOF16 ? f2h(v) : f2bf(v);
    }
}

// =====================================================================
// v [128][1024][64] bf16 -> vT [128][64][1024] bf16
// =====================================================================
__global__ void transpose_v(const unsigned short* __restrict__ v, unsigned short* __restrict__ vT) {
    const int bh = blockIdx.z, d0 = blockIdx.x * 32, s0 = blockIdx.y * 32;
    __shared__ unsigned short t[32][33];
    const int tx = threadIdx.x, ty = threadIdx.y;
    const size_t base = (size_t)bh << 16;
#pragma unroll
    for (int i = 0; i < 4; ++i)
        t[ty + 8 * i][tx] = v[base + (size_t)(s0 + ty + 8 * i) * 64 + d0 + tx];
    __syncthreads();
#pragma unroll
    for (int i = 0; i < 4; ++i)
        vT[base + (size_t)(d0 + ty + 8 * i) * 1024 + s0 + tx] = t[tx][ty + 8 * i];
}

// =====================================================================
// GEMM (B^T form), 2-phase double-buffered (T3 minimum), as in round 8:
//   stage(k+1) -> s_waitcnt vmcnt(4) -> raw s_barrier -> MFMA(k) -> s_barrier.
// =====================================================================
template<int F16IN, int EPI>
__global__ __launch_bounds__(256, 2) void gemm_bt(
    const unsigned short* __restrict__ A,
    const unsigned short* __restrict__ Bt,
    const float* __restrict__ bias,
    unsigned short* __restrict__ C2b,
    const float* __restrict__ resid,
    float* __restrict__ Cf,
    int M, int N, int K, int nbx)
{
    const int bid = blockIdx.x;
    const int cpx = gridDim.x >> 3;
    const int swz = (bid & 7) * cpx + (bid >> 3);
    const int bm = swz / nbx, bn = swz % nbx;
    const int m0 = bm * 128, n0 = bn * 128;

    const int tid = threadIdx.x;
    const int w = tid >> 6, l = tid & 63, g = l >> 4, c = l & 15;
    const int wr = w >> 1, wc = w & 1;

    __shared__ unsigned short As[2][4096];   // 2 x [128][32]
    __shared__ unsigned short Bs[2][4096];

    f32x4 acc[4][4] = {};

    const int arow = tid >> 2, acol = (tid & 3) * 8;
    const unsigned short* Ap  = A  + (size_t)(m0 + arow) * K + acol;
    const unsigned short* Ap2 = A  + (size_t)(m0 + 64 + arow) * K + acol;
    const unsigned short* Bp  = Bt + (size_t)(n0 + arow) * K + acol;
    const unsigned short* Bp2 = Bt + (size_t)(n0 + 64 + arow) * K + acol;

    const int NT = K >> 5;

#define STAGE_GEMM(bufi, koff)                                   \
    do {                                                         \
        gload16(Ap  + (koff), &As[bufi][w * 512]);               \
        gload16(Ap2 + (koff), &As[bufi][2048 + w * 512]);        \
        gload16(Bp  + (koff), &Bs[bufi][w * 512]);               \
        gload16(Bp2 + (koff), &Bs[bufi][2048 + w * 512]);        \
    } while (0)

#define COMPUTE_GEMM(bufi)                                                         \
    do {                                                                           \
        if constexpr (F16IN) {                                                     \
            f16x8 a[4], b[4];                                                      \
            _Pragma("unroll")                                                      \
            for (int mt = 0; mt < 4; ++mt)                                         \
                a[mt] = *(const f16x8*)&As[bufi][(wr * 64 + mt * 16 + c) * 32 + g * 8]; \
            _Pragma("unroll")                                                      \
            for (int nt = 0; nt < 4; ++nt)                                         \
                b[nt] = *(const f16x8*)&Bs[bufi][(wc * 64 + nt * 16 + c) * 32 + g * 8]; \
            _Pragma("unroll")                                                      \
            for (int mt = 0; mt < 4; ++mt)                                         \
                _Pragma("unroll")                                                  \
                for (int nt = 0; nt < 4; ++nt)                                     \
                    acc[mt][nt] = __builtin_amdgcn_mfma_f32_16x16x32_f16(a[mt], b[nt], acc[mt][nt], 0, 0, 0); \
        } else {                                                                   \
            short8 a[4], b[4];                                                     \
            _Pragma("unroll")                                                      \
            for (int mt = 0; mt < 4; ++mt)                                         \
                a[mt] = *(const short8*)&As[bufi][(wr * 64 + mt * 16 + c) * 32 + g * 8]; \
            _Pragma("unroll")                                                      \
            for (int nt = 0; nt < 4; ++nt)                                         \
                b[nt] = *(const short8*)&Bs[bufi][(wc * 64 + nt * 16 + c) * 32 + g * 8]; \
            _Pragma("unroll")                                                      \
            for (int mt = 0; mt < 4; ++mt)                                         \
                _Pragma("unroll")                                                  \
                for (int nt = 0; nt < 4; ++nt)                                     \
                    acc[mt][nt] = __builtin_amdgcn_mfma_f32_16x16x32_bf16(a[mt], b[nt], acc[mt][nt], 0, 0, 0); \
        }                                                                          \
    } while (0)

    STAGE_GEMM(0, 0);

#pragma unroll 2
    for (int kt = 0; kt < NT - 1; ++kt) {
        const int cur = kt & 1;
        STAGE_GEMM(cur ^ 1, (kt + 1) * 32);
        asm volatile("s_waitcnt vmcnt(4)" ::: "memory");
        __builtin_amdgcn_s_barrier();
        __builtin_amdgcn_sched_barrier(0);
        COMPUTE_GEMM(cur);
        __builtin_amdgcn_sched_barrier(0);
        __builtin_amdgcn_s_barrier();
    }
    asm volatile("s_waitcnt vmcnt(0)" ::: "memory");
    __builtin_amdgcn_s_barrier();
    __builtin_amdgcn_sched_barrier(0);
    COMPUTE_GEMM((NT - 1) & 1);

#undef STAGE_GEMM
#undef COMPUTE_GEMM

#pragma unroll
    for (int nt = 0; nt < 4; ++nt) {
        const int col = n0 + wc * 64 + nt * 16 + c;
        const float bs = bias[col];
#pragma unroll
        for (int mt = 0; mt < 4; ++mt) {
            const int row0 = m0 + wr * 64 + mt * 16 + g * 4;
#pragma unroll
            for (int r = 0; r < 4; ++r) {
                const float x = acc[mt][nt][r] + bs;
                const size_t idx = (size_t)(row0 + r) * N + col;
                if constexpr (EPI == 0) {
                    C2b[idx] = F16IN ? f2h(x) : f2bf(x);
                } else {
                    Cf[idx] = x + resid[idx];
                }
            }
        }
    }
}

// =====================================================================
// Attention v11 = r8 (v6) base + explicit software-pipelined loads:
//  - QK^T: 4-deep rotating K-prefetch (ka0/ka1[4], static idx under full
//    unroll) -> load-use distance 4 iterations instead of 0.
//  - PV: 2-deep vT prefetch.
//  - All else identical to r8: swapped QK^T, packed bf16 pks[16],
//    NT stores interleaved into PV, XCD-chunked decode.
// One block = (bh, 16 q-rows); 4 waves x 256 k-cols. Grid = 8192.
// =====================================================================
__global__ __launch_bounds__(256, 4) void attn_kernel(
    const unsigned short* __restrict__ qf,   // f16  [128*1024*64]
    const unsigned short* __restrict__ kf,   // f16  [128*1024*64]
    const unsigned short* __restrict__ vT,   // bf16 [128][64][1024]
    float* __restrict__ attn_out,            // f32  [128][1024][1024]
    unsigned short* __restrict__ ctx)        // bf16 [128*1024*64]
{
    const int L = blockIdx.x;
    const int rb = (L >> 3) & 63;
    const int bh = ((L & 7) << 4) | (L >> 9);

    const int tid = threadIdx.x;
    const int w = tid >> 6, l = tid & 63, g = l >> 4, c = l & 15;
    const int n0 = w * 256;

    __shared__ unsigned short P[16 * 1024];  // 32 KB, XOR-swizzled by (row&7)<<4
    __shared__ float rs_lds[4][16];
    __shared__ float inv_lds[16];

    // Q fragment (B-operand): lane holds Q[row = rb*16 + c][d = g*8 .. +7] (+32)
    const unsigned short* qb = qf + ((size_t)bh << 16) + (size_t)(rb * 16 + c) * 64 + g * 8;
    const f16x8 q0 = *(const f16x8*)(qb);
    const f16x8 q1 = *(const f16x8*)(qb + 32);

    const unsigned short* kb = kf + ((size_t)bh << 16);
    const unsigned swzc = ((unsigned)(c & 7)) << 4;
    const unsigned prow = (unsigned)c * 2048;

    ushort4_t pks[16];
    float rsum = 0.f;

    // ---- QK^T with 4-deep K prefetch ----
    f16x8 ka0[4], ka1[4];
#pragma unroll
    for (int t = 0; t < 4; ++t) {
        const unsigned short* kp = kb + (size_t)(n0 + t * 16 + c) * 64 + g * 8;
        ka0[t] = *(const f16x8*)(kp);
        ka1[t] = *(const f16x8*)(kp + 32);
    }
#pragma unroll
    for (int t = 0; t < 16; ++t) {
        const f16x8 a0 = ka0[t & 3];
        const f16x8 a1 = ka1[t & 3];
        if (t + 4 < 16) {
            const unsigned short* kp = kb + (size_t)(n0 + (t + 4) * 16 + c) * 64 + g * 8;
            ka0[t & 3] = *(const f16x8*)(kp);
            ka1[t & 3] = *(const f16x8*)(kp + 32);
        }
        f32x4 s = {0.f, 0.f, 0.f, 0.f};
        s = __builtin_amdgcn_mfma_f32_16x16x32_f16(a0, q0, s, 0, 0, 0);
        s = __builtin_amdgcn_mfma_f32_16x16x32_f16(a1, q1, s, 0, 0, 0);

        const float p0 = __expf(s[0] * 0.5f);
        const float p1 = __expf(s[1] * 0.5f);
        const float p2 = __expf(s[2] * 0.5f);
        const float p3 = __expf(s[3] * 0.5f);
        rsum += (p0 + p1) + (p2 + p3);

        ushort4_t pk;
        pk.x = f2bf(p0); pk.y = f2bf(p1); pk.z = f2bf(p2); pk.w = f2bf(p3);
        pks[t] = pk;
        // row = c, byte col = n0*2 + t*32 + g*8  (4 consecutive bf16 = 8B)
        *(ushort4_t*)((char*)P + ((prow + (unsigned)(n0 * 2 + t * 32 + g * 8)) ^ swzc)) = pk;
    }

    // row-sum for row c: reduce over the 4 lane-groups (lane-id bits 4,5)
    rsum += __shfl_xor(rsum, 16);
    rsum += __shfl_xor(rsum, 32);
    if (g == 0) rs_lds[w][c] = rsum;
    __syncthreads();                          // also covers P ds_writes
    if (tid < 16)
        inv_lds[tid] = 1.0f / (rs_lds[0][tid] + rs_lds[1][tid] + rs_lds[2][tid] + rs_lds[3][tid]);
    __syncthreads();

    // ---- PV with 2-deep vT prefetch + interleaved NT attention stores ----
    const float inv = inv_lds[c];
    float* ao = attn_out + ((size_t)bh << 20) + (size_t)(rb * 16 + c) * 1024 + n0 + g * 4;
    f32x4 pacc = {0.f, 0.f, 0.f, 0.f};
    const unsigned short* vb = vT + ((size_t)bh << 16) + (size_t)(w * 16 + c) * 1024;

    short8 vbuf[2];
    vbuf[0] = *(const short8*)(vb + 0 * 32 + g * 8);
    vbuf[1] = *(const short8*)(vb + 1 * 32 + g * 8);
#pragma unroll
    for (int ks = 0; ks < 32; ++ks) {
        const short8 a = *(const short8*)((char*)P + ((prow + (unsigned)(ks * 64 + g * 16)) ^ swzc));
        const short8 b = vbuf[ks & 1];
        if (ks + 2 < 32)
            vbuf[ks & 1] = *(const short8*)(vb + (ks + 2) * 32 + g * 8);
        pacc = __builtin_amdgcn_mfma_f32_16x16x32_bf16(a, b, pacc, 0, 0, 0);
        if (ks & 1) {
            const int t = ks >> 1;
            const ushort4_t pk = pks[t];
            f32x4 o;
            o[0] = bf2f(pk.x) * inv;
            o[1] = bf2f(pk.y) * inv;
            o[2] = bf2f(pk.z) * inv;
            o[3] = bf2f(pk.w) * inv;
            __builtin_nontemporal_store(o, (f32x4*)(ao + t * 16));
        }
    }
    unsigned short* cb = ctx + ((size_t)bh << 16) + (size_t)(rb * 16) * 64 + w * 16 + c;
#pragma unroll
    for (int r = 0; r < 4; ++r) {
        const int row = g * 4 + r;
        cb[(size_t)row * 64] = f2bf(pacc[r] * inv_lds[row]);
    }
}

// =====================================================================
// BatchNorm over channels (deterministic two-level reduction)
// =====================================================================
__global__ void bn_stats(const float* __restrict__ x, float* __restrict__ psum, float* __restrict__ psq) {
    const int col = blockIdx.y * 256 + threadIdx.x;   // grid.y = 4
    const int r0 = blockIdx.x * 128;                  // grid.x = 64
    float s = 0.f, q = 0.f;
#pragma unroll 4
    for (int r = 0; r < 128; ++r) {
        const float v = x[(size_t)(r0 + r) * 1024 + col];
        s += v; q += v * v;
    }
    psum[blockIdx.x * 1024 + col] = s;
    psq [blockIdx.x * 1024 + col] = q;
}

__global__ void bn_final(const float* __restrict__ psum, const float* __restrict__ psq,
                         const float* __restrict__ gamma, const float* __restrict__ beta,
                         float* __restrict__ ab) {
    const int cidx = threadIdx.x;   // 1024 threads
    float s = 0.f, q = 0.f;
#pragma unroll 8
    for (int i = 0; i < 64; ++i) { s += psum[i * 1024 + cidx]; q += psq[i * 1024 + cidx]; }
    const float mean = s * (1.0f / 8192.0f);
    const float var  = q * (1.0f / 8192.0f) - mean * mean;
    const float a = gamma[cidx] * rsqrtf(var + 1e-5f);
    ab[cidx]        = a;
    ab[1024 + cidx] = beta[cidx] - mean * a;
}

__global__ void bn_apply(const float4* __restrict__ x4, const float* __restrict__ ab, float4* __restrict__ o4) {
    const int n4 = 2 * 1024 * 1024;
    for (int i = blockIdx.x * blockDim.x + threadIdx.x; i < n4; i += gridDim.x * blockDim.x) {
        const float4 v = x4[i];
        const int c0 = (i & 255) << 2;
        float4 r;
        r.x = v.x * ab[c0 + 0] + ab[1024 + c0 + 0];
        r.y = v.y * ab[c0 + 1] + ab[1024 + c0 + 1];
        r.z = v.z * ab[c0 + 2] + ab[1024 + c0 + 2];
        r.w = v.w * ab[c0 + 3] + ab[1024 + c0 + 3];
        o4[i] = r;
    }
}

// =====================================================================
// launch
// =====================================================================
extern "C" void kernel_launch(void* const* d_in, const int* in_sizes, int n_in,
                              void* d_out, int out_size, void* d_ws, size_t ws_size,
                              hipStream_t stream) {
    (void)in_sizes; (void)n_in; (void)out_size; (void)ws_size;

    const float* key   = (const float*)d_in[0];
    const float* value = (const float*)d_in[1];
    const float* query = (const float*)d_in[2];
    const float* Wk = (const float*)d_in[3];
    const float* bk = (const float*)d_in[4];
    const float* Wv = (const float*)d_in[5];
    const float* bv = (const float*)d_in[6];
    const float* Wq = (const float*)d_in[7];
    const float* bq = (const float*)d_in[8];
    const float* Wf = (const float*)d_in[9];
    const float* bff = (const float*)d_in[10];
    const float* gamma = (const float*)d_in[11];
    const float* beta  = (const float*)d_in[12];

    char* ws = (char*)d_ws;
    const size_t MB = 1u << 20;
    unsigned short* key16   = (unsigned short*)(ws + 0);        // dead after GEMM-k -> ctx
    unsigned short* ctx     = (unsigned short*)(ws + 0);
    unsigned short* query16 = (unsigned short*)(ws + 16 * MB);
    unsigned short* value16 = (unsigned short*)(ws + 32 * MB);
    float*          xbuf    = (float*)(ws + 16 * MB);           // 32 MB
    unsigned short* WkT = (unsigned short*)(ws + 48 * MB);
    unsigned short* WqT = (unsigned short*)(ws + 50 * MB);
    unsigned short* WvT = (unsigned short*)(ws + 52 * MB);
    unsigned short* WfT = (unsigned short*)(ws + 54 * MB);
    unsigned short* kbuf = (unsigned short*)(ws + 56 * MB);
    unsigned short* qbuf = (unsigned short*)(ws + 72 * MB);
    unsigned short* vbuf = (unsigned short*)(ws + 88 * MB);
    float* psum = (float*)(ws + 88 * MB);
    float* psq  = (float*)(ws + 88 * MB + 256 * 1024);
    float* ab   = (float*)(ws + 88 * MB + 512 * 1024);
    unsigned short* vTbuf = (unsigned short*)(ws + 104 * MB);

    float* out0 = (float*)d_out;            // [8M]  normalized output
    float* attn = out0 + 8388608;           // [128M] attention

    const int n4big = 2 * 1024 * 1024;

    // 1) input conversions (single batched launch)
    cvt3_f32_2b<<<dim3(1024, 3), 256, 0, stream>>>(
        (const float4*)key, (const float4*)query, (const float4*)value,
        (ushort4_t*)key16, (ushort4_t*)query16, (ushort4_t*)value16, n4big);

    // 2) weight transposes
    dim3 tb(32, 8), tg(32, 32);
    transpose_cvt<1><<<tg, tb, 0, stream>>>(Wk, WkT, 1024);
    transpose_cvt<1><<<tg, tb, 0, stream>>>(Wq, WqT, 1024);
    transpose_cvt<0><<<tg, tb, 0, stream>>>(Wv, WvT, 1024);
    transpose_cvt<0><<<tg, tb, 0, stream>>>(Wf, WfT, 1024);

    // 3) QKV projections (M=8192, N=1024, K=1024), f16 for q/k, bf16 for v
    gemm_bt<1, 0><<<512, 256, 0, stream>>>(key16,   WkT, bk, kbuf, nullptr, nullptr, 8192, 1024, 1024, 8);
    gemm_bt<1, 0><<<512, 256, 0, stream>>>(query16, WqT, bq, qbuf, nullptr, nullptr, 8192, 1024, 1024, 8);
    gemm_bt<0, 0><<<512, 256, 0, stream>>>(value16, WvT, bv, vbuf, nullptr, nullptr, 8192, 1024, 1024, 8);

    // 4) v -> vT per head-batch
    transpose_v<<<dim3(2, 32, 128), tb, 0, stream>>>(vbuf, vTbuf);

    // 5) attention (writes attention matrix + ctx), XCD-chunked 1-D grid
    attn_kernel<<<8192, 256, 0, stream>>>(qbuf, kbuf, vTbuf, attn, ctx);

    // 6) output projection + residual -> xbuf (f32)
    gemm_bt<0, 1><<<512, 256, 0, stream>>>(ctx, WfT, bff, nullptr, query, xbuf, 8192, 1024, 1024, 8);

    // 7) BatchNorm (deterministic)
    bn_stats<<<dim3(64, 4), 256, 0, stream>>>(xbuf, psum, psq);
    bn_final<<<1, 1024, 0, stream>>>(psum, psq, gamma, beta, ab);
    bn_apply<<<2048, 256, 0, stream>>>((const float4*)xbuf, ab, (float4*)out0);
}

// Round 15
// 428.495 us; speedup vs baseline: 1.1912x; 1.0766x over previous
//
#include <hip/hip_runtime.h>
#include <hip/hip_bf16.h>
#include <stdint.h>

// ---------- types ----------
typedef __attribute__((ext_vector_type(8))) short     short8;   // 8 bf16 (raw bits)
typedef __attribute__((ext_vector_type(8))) _Float16  f16x8;    // 8 fp16
typedef __attribute__((ext_vector_type(4))) float     f32x4;
typedef __attribute__((ext_vector_type(4))) unsigned short ushort4_t;

// ---------- scalar conversion helpers ----------
__device__ inline unsigned short f2bf(float f) {
    unsigned u = __float_as_uint(f);
    u += 0x7fffu + ((u >> 16) & 1u);          // RNE
    return (unsigned short)(u >> 16);
}
__device__ inline float bf2f(unsigned short h) {
    return __uint_as_float(((unsigned)h) << 16);
}
__device__ inline unsigned short f2h(float f) {
    _Float16 h = (_Float16)f;
    unsigned short r;
    __builtin_memcpy(&r, &h, 2);
    return r;
}

// ---------- async global->LDS (width 16) ----------
__device__ inline void gload16(const void* g, void* lds) {
    unsigned loff = (unsigned)(uintptr_t)lds;
    loff = __builtin_amdgcn_readfirstlane(loff);
    auto l = (__attribute__((address_space(3))) unsigned int*)(uintptr_t)loff;
    auto p = (const __attribute__((address_space(1))) unsigned int*)(uintptr_t)g;
    __builtin_amdgcn_global_load_lds(p, l, 16, 0, 0);
}

// =====================================================================
// Batched elementwise f32 -> 2-byte: y=0 key->f16, y=1 query->f16, y=2 value->bf16
// =====================================================================
__global__ void cvt3_f32_2b(const float4* __restrict__ k, const float4* __restrict__ q,
                            const float4* __restrict__ v,
                            ushort4_t* __restrict__ k16, ushort4_t* __restrict__ q16,
                            ushort4_t* __restrict__ v16, int n4) {
    const int which = blockIdx.y;
    const float4* in  = which == 0 ? k   : which == 1 ? q   : v;
    ushort4_t*    out = which == 0 ? k16 : which == 1 ? q16 : v16;
    const bool tof16 = (which < 2);
    for (int i = blockIdx.x * blockDim.x + threadIdx.x; i < n4; i += gridDim.x * blockDim.x) {
        float4 vv = in[i];
        ushort4_t r;
        if (tof16) { r.x = f2h(vv.x);  r.y = f2h(vv.y);  r.z = f2h(vv.z);  r.w = f2h(vv.w); }
        else       { r.x = f2bf(vv.x); r.y = f2bf(vv.y); r.z = f2bf(vv.z); r.w = f2bf(vv.w); }
        out[i] = r;
    }
}

// =====================================================================
// Weight transpose + convert: W[dim][dim] f32 -> WT[n][k] 2-byte
// =====================================================================
template<int TOF16>
__global__ void transpose_cvt(const float* __restrict__ W, unsigned short* __restrict__ WT, int dim) {
    __shared__ float t[32][33];
    const int bx = blockIdx.x * 32, by = blockIdx.y * 32;   // bx: n, by: k
    const int tx = threadIdx.x, ty = threadIdx.y;
#pragma unroll
    for (int i = 0; i < 4; ++i)
        t[ty + 8 * i][tx] = W[(size_t)(by + ty + 8 * i) * dim + bx + tx];
    __syncthreads();
#pragma unroll
    for (int i = 0; i < 4; ++i) {
        float v = t[tx][ty + 8 * i];
        WT[(size_t)(bx + ty + 8 * i) * dim + by + tx] = TOF16 ? f2h(v) : f2bf(v);
    }
}

// =====================================================================
// v [128][1024][64] bf16 -> vT [128][64][1024] bf16
// =====================================================================
__global__ void transpose_v(const unsigned short* __restrict__ v, unsigned short* __restrict__ vT) {
    const int bh = blockIdx.z, d0 = blockIdx.x * 32, s0 = blockIdx.y * 32;
    __shared__ unsigned short t[32][33];
    const int tx = threadIdx.x, ty = threadIdx.y;
    const size_t base = (size_t)bh << 16;
#pragma unroll
    for (int i = 0; i < 4; ++i)
        t[ty + 8 * i][tx] = v[base + (size_t)(s0 + ty + 8 * i) * 64 + d0 + tx];
    __syncthreads();
#pragma unroll
    for (int i = 0; i < 4; ++i)
        vT[base + (size_t)(d0 + ty + 8 * i) * 1024 + s0 + tx] = t[tx][ty + 8 * i];
}

// =====================================================================
// GEMM (B^T form), 2-phase double-buffered (T3 minimum), as in round 8:
//   stage(k+1) -> s_waitcnt vmcnt(4) -> raw s_barrier -> MFMA(k) -> s_barrier.
// =====================================================================
template<int F16IN, int EPI>
__global__ __launch_bounds__(256, 2) void gemm_bt(
    const unsigned short* __restrict__ A,
    const unsigned short* __restrict__ Bt,
    const float* __restrict__ bias,
    unsigned short* __restrict__ C2b,
    const float* __restrict__ resid,
    float* __restrict__ Cf,
    int M, int N, int K, int nbx)
{
    const int bid = blockIdx.x;
    const int cpx = gridDim.x >> 3;
    const int swz = (bid & 7) * cpx + (bid >> 3);
    const int bm = swz / nbx, bn = swz % nbx;
    const int m0 = bm * 128, n0 = bn * 128;

    const int tid = threadIdx.x;
    const int w = tid >> 6, l = tid & 63, g = l >> 4, c = l & 15;
    const int wr = w >> 1, wc = w & 1;

    __shared__ unsigned short As[2][4096];   // 2 x [128][32]
    __shared__ unsigned short Bs[2][4096];

    f32x4 acc[4][4] = {};

    const int arow = tid >> 2, acol = (tid & 3) * 8;
    const unsigned short* Ap  = A  + (size_t)(m0 + arow) * K + acol;
    const unsigned short* Ap2 = A  + (size_t)(m0 + 64 + arow) * K + acol;
    const unsigned short* Bp  = Bt + (size_t)(n0 + arow) * K + acol;
    const unsigned short* Bp2 = Bt + (size_t)(n0 + 64 + arow) * K + acol;

    const int NT = K >> 5;

#define STAGE_GEMM(bufi, koff)                                   \
    do {                                                         \
        gload16(Ap  + (koff), &As[bufi][w * 512]);               \
        gload16(Ap2 + (koff), &As[bufi][2048 + w * 512]);        \
        gload16(Bp  + (koff), &Bs[bufi][w * 512]);               \
        gload16(Bp2 + (koff), &Bs[bufi][2048 + w * 512]);        \
    } while (0)

#define COMPUTE_GEMM(bufi)                                                         \
    do {                                                                           \
        if constexpr (F16IN) {                                                     \
            f16x8 a[4], b[4];                                                      \
            _Pragma("unroll")                                                      \
            for (int mt = 0; mt < 4; ++mt)                                         \
                a[mt] = *(const f16x8*)&As[bufi][(wr * 64 + mt * 16 + c) * 32 + g * 8]; \
            _Pragma("unroll")                                                      \
            for (int nt = 0; nt < 4; ++nt)                                         \
                b[nt] = *(const f16x8*)&Bs[bufi][(wc * 64 + nt * 16 + c) * 32 + g * 8]; \
            _Pragma("unroll")                                                      \
            for (int mt = 0; mt < 4; ++mt)                                         \
                _Pragma("unroll")                                                  \
                for (int nt = 0; nt < 4; ++nt)                                     \
                    acc[mt][nt] = __builtin_amdgcn_mfma_f32_16x16x32_f16(a[mt], b[nt], acc[mt][nt], 0, 0, 0); \
        } else {                                                                   \
            short8 a[4], b[4];                                                     \
            _Pragma("unroll")                                                      \
            for (int mt = 0; mt < 4; ++mt)                                         \
                a[mt] = *(const short8*)&As[bufi][(wr * 64 + mt * 16 + c) * 32 + g * 8]; \
            _Pragma("unroll")                                                      \
            for (int nt = 0; nt < 4; ++nt)                                         \
                b[nt] = *(const short8*)&Bs[bufi][(wc * 64 + nt * 16 + c) * 32 + g * 8]; \
            _Pragma("unroll")                                                      \
            for (int mt = 0; mt < 4; ++mt)                                         \
                _Pragma("unroll")                                                  \
                for (int nt = 0; nt < 4; ++nt)                                     \
                    acc[mt][nt] = __builtin_amdgcn_mfma_f32_16x16x32_bf16(a[mt], b[nt], acc[mt][nt], 0, 0, 0); \
        }                                                                          \
    } while (0)

    STAGE_GEMM(0, 0);

#pragma unroll 2
    for (int kt = 0; kt < NT - 1; ++kt) {
        const int cur = kt & 1;
        STAGE_GEMM(cur ^ 1, (kt + 1) * 32);
        asm volatile("s_waitcnt vmcnt(4)" ::: "memory");
        __builtin_amdgcn_s_barrier();
        __builtin_amdgcn_sched_barrier(0);
        COMPUTE_GEMM(cur);
        __builtin_amdgcn_sched_barrier(0);
        __builtin_amdgcn_s_barrier();
    }
    asm volatile("s_waitcnt vmcnt(0)" ::: "memory");
    __builtin_amdgcn_s_barrier();
    __builtin_amdgcn_sched_barrier(0);
    COMPUTE_GEMM((NT - 1) & 1);

#undef STAGE_GEMM
#undef COMPUTE_GEMM

#pragma unroll
    for (int nt = 0; nt < 4; ++nt) {
        const int col = n0 + wc * 64 + nt * 16 + c;
        const float bs = bias[col];
#pragma unroll
        for (int mt = 0; mt < 4; ++mt) {
            const int row0 = m0 + wr * 64 + mt * 16 + g * 4;
#pragma unroll
            for (int r = 0; r < 4; ++r) {
                const float x = acc[mt][nt][r] + bs;
                const size_t idx = (size_t)(row0 + r) * N + col;
                if constexpr (EPI == 0) {
                    C2b[idx] = F16IN ? f2h(x) : f2bf(x);
                } else {
                    Cf[idx] = x + resid[idx];
                }
            }
        }
    }
}

// =====================================================================
// Attention v12 = r8 (v6) base + FULL-LINE NT stores via __shfl:
//  For each t-pair (t0=2p, t1=2p+1) the wave's pks data covers 16 rows x
//  128B. Two NT store instructions re-routed by shuffle: store A = rows
//  0-7 (lane l -> row l>>3, chunk l&7; src lane ((j&3)<<4)|row, value
//  pks[t0] if j<4 else pks[t1]); store B = rows 8-15. Each instruction
//  covers 8 complete, 128B-aligned lines -> no partial-sector NT write
//  amplification (r10: 64B sectors = 983MB vs clean 545MB), while NT
//  still keeps the 512MB stream out of L2 (r12: plain stores +67us).
//  Interleave cadence unchanged (stores at ks%4==1,3 inside PV).
// One block = (bh, 16 q-rows); 4 waves x 256 k-cols. Grid = 8192.
// =====================================================================
__global__ __launch_bounds__(256, 4) void attn_kernel(
    const unsigned short* __restrict__ qf,   // f16  [128*1024*64]
    const unsigned short* __restrict__ kf,   // f16  [128*1024*64]
    const unsigned short* __restrict__ vT,   // bf16 [128][64][1024]
    float* __restrict__ attn_out,            // f32  [128][1024][1024]
    unsigned short* __restrict__ ctx)        // bf16 [128*1024*64]
{
    const int L = blockIdx.x;
    const int rb = (L >> 3) & 63;
    const int bh = ((L & 7) << 4) | (L >> 9);

    const int tid = threadIdx.x;
    const int w = tid >> 6, l = tid & 63, g = l >> 4, c = l & 15;
    const int n0 = w * 256;

    __shared__ unsigned short P[16 * 1024];  // 32 KB, XOR-swizzled by (row&7)<<4
    __shared__ float rs_lds[4][16];
    __shared__ float inv_lds[16];

    // Q fragment (B-operand): lane holds Q[row = rb*16 + c][d = g*8 .. +7] (+32)
    const unsigned short* qb = qf + ((size_t)bh << 16) + (size_t)(rb * 16 + c) * 64 + g * 8;
    const f16x8 q0 = *(const f16x8*)(qb);
    const f16x8 q1 = *(const f16x8*)(qb + 32);

    const unsigned short* kb = kf + ((size_t)bh << 16);
    const unsigned swzc = ((unsigned)(c & 7)) << 4;
    const unsigned prow = (unsigned)c * 2048;

    ushort4_t pks[16];
    float rsum = 0.f;

    // QK^T: per t, A-operand = K rows (= attention cols) n0+t*16+c, d-chunk g*8.
    // Output: lane holds score[q = c][kcol = n0 + t*16 + g*4 + r].
#pragma unroll
    for (int t = 0; t < 16; ++t) {
        const unsigned short* kp = kb + (size_t)(n0 + t * 16 + c) * 64 + g * 8;
        const f16x8 a0 = *(const f16x8*)(kp);
        const f16x8 a1 = *(const f16x8*)(kp + 32);
        f32x4 s = {0.f, 0.f, 0.f, 0.f};
        s = __builtin_amdgcn_mfma_f32_16x16x32_f16(a0, q0, s, 0, 0, 0);
        s = __builtin_amdgcn_mfma_f32_16x16x32_f16(a1, q1, s, 0, 0, 0);

        const float p0 = __expf(s[0] * 0.5f);
        const float p1 = __expf(s[1] * 0.5f);
        const float p2 = __expf(s[2] * 0.5f);
        const float p3 = __expf(s[3] * 0.5f);
        rsum += (p0 + p1) + (p2 + p3);

        ushort4_t pk;
        pk.x = f2bf(p0); pk.y = f2bf(p1); pk.z = f2bf(p2); pk.w = f2bf(p3);
        pks[t] = pk;
        // row = c, byte col = n0*2 + t*32 + g*8  (4 consecutive bf16 = 8B)
        *(ushort4_t*)((char*)P + ((prow + (unsigned)(n0 * 2 + t * 32 + g * 8)) ^ swzc)) = pk;
    }

    // row-sum for row c: reduce over the 4 lane-groups (lane-id bits 4,5)
    rsum += __shfl_xor(rsum, 16);
    rsum += __shfl_xor(rsum, 32);
    if (g == 0) rs_lds[w][c] = rsum;
    __syncthreads();                          // also covers P ds_writes
    if (tid < 16)
        inv_lds[tid] = 1.0f / (rs_lds[0][tid] + rs_lds[1][tid] + rs_lds[2][tid] + rs_lds[3][tid]);
    __syncthreads();

    // store-routing constants: lane l -> (row slot, chunk) for full-line stores
    const int rA = l >> 3, jj = l & 7;          // store A: rows 0-7
    const int rB = 8 + rA;                      // store B: rows 8-15
    const int slA = ((jj & 3) << 4) | rA;       // source lane (g=jj&3, c=row)
    const int slB = ((jj & 3) << 4) | rB;
    const float invA = inv_lds[rA];
    const float invB = inv_lds[rB];
    float* aoA = attn_out + ((size_t)bh << 20) + (size_t)(rb * 16 + rA) * 1024 + n0;
    float* aoB = attn_out + ((size_t)bh << 20) + (size_t)(rb * 16 + rB) * 1024 + n0;

    // PV with interleaved FULL-LINE NT attention stores.
    // PV: wave w owns output cols d = w*16 .. +15, K = 1024.
    f32x4 pacc = {0.f, 0.f, 0.f, 0.f};
    const unsigned short* vb = vT + ((size_t)bh << 16) + (size_t)(w * 16 + c) * 1024;
#pragma unroll
    for (int ks = 0; ks < 32; ++ks) {
        const short8 a = *(const short8*)((char*)P + ((prow + (unsigned)(ks * 64 + g * 16)) ^ swzc));
        const short8 b = *(const short8*)(vb + ks * 32 + g * 8);
        pacc = __builtin_amdgcn_mfma_f32_16x16x32_bf16(a, b, pacc, 0, 0, 0);
        if (ks & 1) {
            const int p = ks >> 2;              // t-pair index 0..7
            const int t0 = 2 * p, t1 = t0 + 1;
            const bool isA = ((ks & 3) == 1);   // A at ks%4==1, B at ks%4==3
            const int sl = isA ? slA : slB;
            unsigned long long e0, e1;
            __builtin_memcpy(&e0, &pks[t0], 8);
            __builtin_memcpy(&e1, &pks[t1], 8);
            const unsigned long long ea = __shfl(e0, sl, 64);
            const unsigned long long eb = __shfl(e1, sl, 64);
            const unsigned long long sel = (jj < 4) ? ea : eb;
            const float inv2 = isA ? invA : invB;
            f32x4 o;
            o[0] = bf2f((unsigned short)(sel      )) * inv2;
            o[1] = bf2f((unsigned short)(sel >> 16)) * inv2;
            o[2] = bf2f((unsigned short)(sel >> 32)) * inv2;
            o[3] = bf2f((unsigned short)(sel >> 48)) * inv2;
            float* dst = (isA ? aoA : aoB) + p * 32 + jj * 4;
            __builtin_nontemporal_store(o, (f32x4*)dst);
        }
    }
    unsigned short* cb = ctx + ((size_t)bh << 16) + (size_t)(rb * 16) * 64 + w * 16 + c;
#pragma unroll
    for (int r = 0; r < 4; ++r) {
        const int row = g * 4 + r;
        cb[(size_t)row * 64] = f2bf(pacc[r] * inv_lds[row]);
    }
}

// =====================================================================
// BatchNorm over channels (deterministic two-level reduction)
// =====================================================================
__global__ void bn_stats(const float* __restrict__ x, float* __restrict__ psum, float* __restrict__ psq) {
    const int col = blockIdx.y * 256 + threadIdx.x;   // grid.y = 4
    const int r0 = blockIdx.x * 128;                  // grid.x = 64
    float s = 0.f, q = 0.f;
#pragma unroll 4
    for (int r = 0; r < 128; ++r) {
        const float v = x[(size_t)(r0 + r) * 1024 + col];
        s += v; q += v * v;
    }
    psum[blockIdx.x * 1024 + col] = s;
    psq [blockIdx.x * 1024 + col] = q;
}

__global__ void bn_final(const float* __restrict__ psum, const float* __restrict__ psq,
                         const float* __restrict__ gamma, const float* __restrict__ beta,
                         float* __restrict__ ab) {
    const int cidx = threadIdx.x;   // 1024 threads
    float s = 0.f, q = 0.f;
#pragma unroll 8
    for (int i = 0; i < 64; ++i) { s += psum[i * 1024 + cidx]; q += psq[i * 1024 + cidx]; }
    const float mean = s * (1.0f / 8192.0f);
    const float var  = q * (1.0f / 8192.0f) - mean * mean;
    const float a = gamma[cidx] * rsqrtf(var + 1e-5f);
    ab[cidx]        = a;
    ab[1024 + cidx] = beta[cidx] - mean * a;
}

__global__ void bn_apply(const float4* __restrict__ x4, const float* __restrict__ ab, float4* __restrict__ o4) {
    const int n4 = 2 * 1024 * 1024;
    for (int i = blockIdx.x * blockDim.x + threadIdx.x; i < n4; i += gridDim.x * blockDim.x) {
        const float4 v = x4[i];
        const int c0 = (i & 255) << 2;
        float4 r;
        r.x = v.x * ab[c0 + 0] + ab[1024 + c0 + 0];
        r.y = v.y * ab[c0 + 1] + ab[1024 + c0 + 1];
        r.z = v.z * ab[c0 + 2] + ab[1024 + c0 + 2];
        r.w = v.w * ab[c0 + 3] + ab[1024 + c0 + 3];
        o4[i] = r;
    }
}

// =====================================================================
// launch
// =====================================================================
extern "C" void kernel_launch(void* const* d_in, const int* in_sizes, int n_in,
                              void* d_out, int out_size, void* d_ws, size_t ws_size,
                              hipStream_t stream) {
    (void)in_sizes; (void)n_in; (void)out_size; (void)ws_size;

    const float* key   = (const float*)d_in[0];
    const float* value = (const float*)d_in[1];
    const float* query = (const float*)d_in[2];
    const float* Wk = (const float*)d_in[3];
    const float* bk = (const float*)d_in[4];
    const float* Wv = (const float*)d_in[5];
    const float* bv = (const float*)d_in[6];
    const float* Wq = (const float*)d_in[7];
    const float* bq = (const float*)d_in[8];
    const float* Wf = (const float*)d_in[9];
    const float* bff = (const float*)d_in[10];
    const float* gamma = (const float*)d_in[11];
    const float* beta  = (const float*)d_in[12];

    char* ws = (char*)d_ws;
    const size_t MB = 1u << 20;
    unsigned short* key16   = (unsigned short*)(ws + 0);        // dead after GEMM-k -> ctx
    unsigned short* ctx     = (unsigned short*)(ws + 0);
    unsigned short* query16 = (unsigned short*)(ws + 16 * MB);
    unsigned short* value16 = (unsigned short*)(ws + 32 * MB);
    float*          xbuf    = (float*)(ws + 16 * MB);           // 32 MB
    unsigned short* WkT = (unsigned short*)(ws + 48 * MB);
    unsigned short* WqT = (unsigned short*)(ws + 50 * MB);
    unsigned short* WvT = (unsigned short*)(ws + 52 * MB);
    unsigned short* WfT = (unsigned short*)(ws + 54 * MB);
    unsigned short* kbuf = (unsigned short*)(ws + 56 * MB);
    unsigned short* qbuf = (unsigned short*)(ws + 72 * MB);
    unsigned short* vbuf = (unsigned short*)(ws + 88 * MB);
    float* psum = (float*)(ws + 88 * MB);
    float* psq  = (float*)(ws + 88 * MB + 256 * 1024);
    float* ab   = (float*)(ws + 88 * MB + 512 * 1024);
    unsigned short* vTbuf = (unsigned short*)(ws + 104 * MB);

    float* out0 = (float*)d_out;            // [8M]  normalized output
    float* attn = out0 + 8388608;           // [128M] attention

    const int n4big = 2 * 1024 * 1024;

    // 1) input conversions (single batched launch)
    cvt3_f32_2b<<<dim3(1024, 3), 256, 0, stream>>>(
        (const float4*)key, (const float4*)query, (const float4*)value,
        (ushort4_t*)key16, (ushort4_t*)query16, (ushort4_t*)value16, n4big);

    // 2) weight transposes
    dim3 tb(32, 8), tg(32, 32);
    transpose_cvt<1><<<tg, tb, 0, stream>>>(Wk, WkT, 1024);
    transpose_cvt<1><<<tg, tb, 0, stream>>>(Wq, WqT, 1024);
    transpose_cvt<0><<<tg, tb, 0, stream>>>(Wv, WvT, 1024);
    transpose_cvt<0><<<tg, tb, 0, stream>>>(Wf, WfT, 1024);

    // 3) QKV projections (M=8192, N=1024, K=1024), f16 for q/k, bf16 for v
    gemm_bt<1, 0><<<512, 256, 0, stream>>>(key16,   WkT, bk, kbuf, nullptr, nullptr, 8192, 1024, 1024, 8);
    gemm_bt<1, 0><<<512, 256, 0, stream>>>(query16, WqT, bq, qbuf, nullptr, nullptr, 8192, 1024, 1024, 8);
    gemm_bt<0, 0><<<512, 256, 0, stream>>>(value16, WvT, bv, vbuf, nullptr, nullptr, 8192, 1024, 1024, 8);

    // 4) v -> vT per head-batch
    transpose_v<<<dim3(2, 32, 128), tb, 0, stream>>>(vbuf, vTbuf);

    // 5) attention (writes attention matrix + ctx), XCD-chunked 1-D grid
    attn_kernel<<<8192, 256, 0, stream>>>(qbuf, kbuf, vTbuf, attn, ctx);

    // 6) output projection + residual -> xbuf (f32)
    gemm_bt<0, 1><<<512, 256, 0, stream>>>(ctx, WfT, bff, nullptr, query, xbuf, 8192, 1024, 1024, 8);

    // 7) BatchNorm (deterministic)
    bn_stats<<<dim3(64, 4), 256, 0, stream>>>(xbuf, psum, psq);
    bn_final<<<1, 1024, 0, stream>>>(psum, psq, gamma, beta, ab);
    bn_apply<<<2048, 256, 0, stream>>>((const float4*)xbuf, ab, (float4*)out0);
}

// Round 16
// 425.999 us; speedup vs baseline: 1.1982x; 1.0059x over previous
//
#include <hip/hip_runtime.h>
#include <hip/hip_bf16.h>
#include <stdint.h>

// ---------- types ----------
typedef __attribute__((ext_vector_type(8))) short     short8;   // 8 bf16 (raw bits)
typedef __attribute__((ext_vector_type(8))) _Float16  f16x8;    // 8 fp16
typedef __attribute__((ext_vector_type(4))) float     f32x4;
typedef __attribute__((ext_vector_type(4))) unsigned short ushort4_t;

// ---------- scalar conversion helpers ----------
__device__ inline unsigned short f2bf(float f) {
    unsigned u = __float_as_uint(f);
    u += 0x7fffu + ((u >> 16) & 1u);          // RNE
    return (unsigned short)(u >> 16);
}
__device__ inline float bf2f(unsigned short h) {
    return __uint_as_float(((unsigned)h) << 16);
}
__device__ inline unsigned short f2h(float f) {
    _Float16 h = (_Float16)f;
    unsigned short r;
    __builtin_memcpy(&r, &h, 2);
    return r;
}

// ---------- async global->LDS (width 16) ----------
__device__ inline void gload16(const void* g, void* lds) {
    unsigned loff = (unsigned)(uintptr_t)lds;
    loff = __builtin_amdgcn_readfirstlane(loff);
    auto l = (__attribute__((address_space(3))) unsigned int*)(uintptr_t)loff;
    auto p = (const __attribute__((address_space(1))) unsigned int*)(uintptr_t)g;
    __builtin_amdgcn_global_load_lds(p, l, 16, 0, 0);
}

// =====================================================================
// Batched elementwise f32 -> 2-byte: y=0 key->f16, y=1 query->f16, y=2 value->bf16
// =====================================================================
__global__ void cvt3_f32_2b(const float4* __restrict__ k, const float4* __restrict__ q,
                            const float4* __restrict__ v,
                            ushort4_t* __restrict__ k16, ushort4_t* __restrict__ q16,
                            ushort4_t* __restrict__ v16, int n4) {
    const int which = blockIdx.y;
    const float4* in  = which == 0 ? k   : which == 1 ? q   : v;
    ushort4_t*    out = which == 0 ? k16 : which == 1 ? q16 : v16;
    const bool tof16 = (which < 2);
    for (int i = blockIdx.x * blockDim.x + threadIdx.x; i < n4; i += gridDim.x * blockDim.x) {
        float4 vv = in[i];
        ushort4_t r;
        if (tof16) { r.x = f2h(vv.x);  r.y = f2h(vv.y);  r.z = f2h(vv.z);  r.w = f2h(vv.w); }
        else       { r.x = f2bf(vv.x); r.y = f2bf(vv.y); r.z = f2bf(vv.z); r.w = f2bf(vv.w); }
        out[i] = r;
    }
}

// =====================================================================
// Batched weight transpose + convert: 4 weights in one launch.
// blockIdx.z: 0=Wk(f16) 1=Wq(f16) 2=Wv(bf16) 3=Wf(bf16)
// =====================================================================
__global__ void transpose_cvt4(const float* __restrict__ Wk, const float* __restrict__ Wq,
                               const float* __restrict__ Wv, const float* __restrict__ Wf,
                               unsigned short* __restrict__ WkT, unsigned short* __restrict__ WqT,
                               unsigned short* __restrict__ WvT, unsigned short* __restrict__ WfT) {
    const int which = blockIdx.z;
    const float* W = which == 0 ? Wk : which == 1 ? Wq : which == 2 ? Wv : Wf;
    unsigned short* WT = which == 0 ? WkT : which == 1 ? WqT : which == 2 ? WvT : WfT;
    const bool tof16 = (which < 2);
    const int dim = 1024;

    __shared__ float t[32][33];
    const int bx = blockIdx.x * 32, by = blockIdx.y * 32;   // bx: n, by: k
    const int tx = threadIdx.x, ty = threadIdx.y;
#pragma unroll
    for (int i = 0; i < 4; ++i)
        t[ty + 8 * i][tx] = W[(size_t)(by + ty + 8 * i) * dim + bx + tx];
    __syncthreads();
#pragma unroll
    for (int i = 0; i < 4; ++i) {
        float v = t[tx][ty + 8 * i];
        WT[(size_t)(bx + ty + 8 * i) * dim + by + tx] = tof16 ? f2h(v) : f2bf(v);
    }
}

// =====================================================================
// v [128][1024][64] bf16 -> vT [128][64][1024] bf16
// =====================================================================
__global__ void transpose_v(const unsigned short* __restrict__ v, unsigned short* __restrict__ vT) {
    const int bh = blockIdx.z, d0 = blockIdx.x * 32, s0 = blockIdx.y * 32;
    __shared__ unsigned short t[32][33];
    const int tx = threadIdx.x, ty = threadIdx.y;
    const size_t base = (size_t)bh << 16;
#pragma unroll
    for (int i = 0; i < 4; ++i)
        t[ty + 8 * i][tx] = v[base + (size_t)(s0 + ty + 8 * i) * 64 + d0 + tx];
    __syncthreads();
#pragma unroll
    for (int i = 0; i < 4; ++i)
        vT[base + (size_t)(d0 + ty + 8 * i) * 1024 + s0 + tx] = t[tx][ty + 8 * i];
}

// =====================================================================
// GEMM (B^T form), 2-phase double-buffered, BK=64 (halved barrier count
// vs round 8's BK=32 -> 16 K-tiles, 32 MFMA per barrier pair):
//   stage(k+1) [8 gload16/wave] -> s_waitcnt vmcnt(8) -> s_barrier ->
//   MFMA(k) x32 -> s_barrier.
// LDS 64KB (2 bufs x [128][64] x A,B), 2 blocks/CU.
// EPI 0: store 2-byte (f16/bf16 per F16IN). EPI 1: f32 store of acc+bias+resid.
// =====================================================================
template<int F16IN, int EPI>
__global__ __launch_bounds__(256, 2) void gemm_bt(
    const unsigned short* __restrict__ A,
    const unsigned short* __restrict__ Bt,
    const float* __restrict__ bias,
    unsigned short* __restrict__ C2b,
    const float* __restrict__ resid,
    float* __restrict__ Cf,
    int M, int N, int K, int nbx)
{
    const int bid = blockIdx.x;
    const int cpx = gridDim.x >> 3;
    const int swz = (bid & 7) * cpx + (bid >> 3);
    const int bm = swz / nbx, bn = swz % nbx;
    const int m0 = bm * 128, n0 = bn * 128;

    const int tid = threadIdx.x;
    const int w = tid >> 6, l = tid & 63, g = l >> 4, c = l & 15;
    const int wr = w >> 1, wc = w & 1;

    __shared__ unsigned short As[2][8192];   // 2 x [128][64]
    __shared__ unsigned short Bs[2][8192];

    f32x4 acc[4][4] = {};

    // chunk-linear staging: chunk = i*256 + tid; row = chunk>>3, col8 = chunk&7
    const int srow = tid >> 3, scol = (tid & 7) * 8;
    const unsigned short* ApS = A  + (size_t)(m0 + srow) * K + scol;
    const unsigned short* BpS = Bt + (size_t)(n0 + srow) * K + scol;

    const int NT = K >> 6;   // 64-wide K-steps

#define STAGE_GEMM(bufi, koff)                                                \
    do {                                                                      \
        _Pragma("unroll")                                                     \
        for (int i = 0; i < 4; ++i) {                                         \
            gload16(ApS + (size_t)i * 32 * K + (koff), &As[bufi][(i * 256 + tid - l) * 8]); \
            gload16(BpS + (size_t)i * 32 * K + (koff), &Bs[bufi][(i * 256 + tid - l) * 8]); \
        }                                                                     \
    } while (0)
    // LDS dest for instr i, wave w: element offset (i*256 + w*64)*8 (=chunk*8,
    // lane*16B auto-added); global row = (i*256+tid)>>3 = i*32 + srow.

#define COMPUTE_GEMM(bufi)                                                         \
    do {                                                                           \
        _Pragma("unroll")                                                          \
        for (int kk = 0; kk < 2; ++kk) {                                           \
            if constexpr (F16IN) {                                                 \
                f16x8 a[4], b[4];                                                  \
                _Pragma("unroll")                                                  \
                for (int mt = 0; mt < 4; ++mt)                                     \
                    a[mt] = *(const f16x8*)&As[bufi][(wr * 64 + mt * 16 + c) * 64 + kk * 32 + g * 8]; \
                _Pragma("unroll")                                                  \
                for (int nt = 0; nt < 4; ++nt)                                     \
                    b[nt] = *(const f16x8*)&Bs[bufi][(wc * 64 + nt * 16 + c) * 64 + kk * 32 + g * 8]; \
                _Pragma("unroll")                                                  \
                for (int mt = 0; mt < 4; ++mt)                                     \
                    _Pragma("unroll")                                              \
                    for (int nt = 0; nt < 4; ++nt)                                 \
                        acc[mt][nt] = __builtin_amdgcn_mfma_f32_16x16x32_f16(a[mt], b[nt], acc[mt][nt], 0, 0, 0); \
            } else {                                                               \
                short8 a[4], b[4];                                                 \
                _Pragma("unroll")                                                  \
                for (int mt = 0; mt < 4; ++mt)                                     \
                    a[mt] = *(const short8*)&As[bufi][(wr * 64 + mt * 16 + c) * 64 + kk * 32 + g * 8]; \
                _Pragma("unroll")                                                  \
                for (int nt = 0; nt < 4; ++nt)                                     \
                    b[nt] = *(const short8*)&Bs[bufi][(wc * 64 + nt * 16 + c) * 64 + kk * 32 + g * 8]; \
                _Pragma("unroll")                                                  \
                for (int mt = 0; mt < 4; ++mt)                                     \
                    _Pragma("unroll")                                              \
                    for (int nt = 0; nt < 4; ++nt)                                 \
                        acc[mt][nt] = __builtin_amdgcn_mfma_f32_16x16x32_bf16(a[mt], b[nt], acc[mt][nt], 0, 0, 0); \
            }                                                                      \
        }                                                                          \
    } while (0)

    STAGE_GEMM(0, 0);

#pragma unroll 2
    for (int kt = 0; kt < NT - 1; ++kt) {
        const int cur = kt & 1;
        STAGE_GEMM(cur ^ 1, (kt + 1) * 64);
        asm volatile("s_waitcnt vmcnt(8)" ::: "memory");  // current tile's 8 loads done
        __builtin_amdgcn_s_barrier();
        __builtin_amdgcn_sched_barrier(0);
        COMPUTE_GEMM(cur);
        __builtin_amdgcn_sched_barrier(0);
        __builtin_amdgcn_s_barrier();
    }
    asm volatile("s_waitcnt vmcnt(0)" ::: "memory");
    __builtin_amdgcn_s_barrier();
    __builtin_amdgcn_sched_barrier(0);
    COMPUTE_GEMM((NT - 1) & 1);

#undef STAGE_GEMM
#undef COMPUTE_GEMM

#pragma unroll
    for (int nt = 0; nt < 4; ++nt) {
        const int col = n0 + wc * 64 + nt * 16 + c;
        const float bs = bias[col];
#pragma unroll
        for (int mt = 0; mt < 4; ++mt) {
            const int row0 = m0 + wr * 64 + mt * 16 + g * 4;
#pragma unroll
            for (int r = 0; r < 4; ++r) {
                const float x = acc[mt][nt][r] + bs;
                const size_t idx = (size_t)(row0 + r) * N + col;
                if constexpr (EPI == 0) {
                    C2b[idx] = F16IN ? f2h(x) : f2bf(x);
                } else {
                    Cf[idx] = x + resid[idx];
                }
            }
        }
    }
}

// =====================================================================
// Attention v12 (round 14, best known): swapped QK^T, packed bf16
// pks[16], FULL-LINE NT stores via __shfl interleaved into PV,
// XCD-chunked decode. One block = (bh, 16 q-rows); grid = 8192.
// =====================================================================
__global__ __launch_bounds__(256, 4) void attn_kernel(
    const unsigned short* __restrict__ qf,   // f16  [128*1024*64]
    const unsigned short* __restrict__ kf,   // f16  [128*1024*64]
    const unsigned short* __restrict__ vT,   // bf16 [128][64][1024]
    float* __restrict__ attn_out,            // f32  [128][1024][1024]
    unsigned short* __restrict__ ctx)        // bf16 [128*1024*64]
{
    const int L = blockIdx.x;
    const int rb = (L >> 3) & 63;
    const int bh = ((L & 7) << 4) | (L >> 9);

    const int tid = threadIdx.x;
    const int w = tid >> 6, l = tid & 63, g = l >> 4, c = l & 15;
    const int n0 = w * 256;

    __shared__ unsigned short P[16 * 1024];  // 32 KB, XOR-swizzled by (row&7)<<4
    __shared__ float rs_lds[4][16];
    __shared__ float inv_lds[16];

    // Q fragment (B-operand): lane holds Q[row = rb*16 + c][d = g*8 .. +7] (+32)
    const unsigned short* qb = qf + ((size_t)bh << 16) + (size_t)(rb * 16 + c) * 64 + g * 8;
    const f16x8 q0 = *(const f16x8*)(qb);
    const f16x8 q1 = *(const f16x8*)(qb + 32);

    const unsigned short* kb = kf + ((size_t)bh << 16);
    const unsigned swzc = ((unsigned)(c & 7)) << 4;
    const unsigned prow = (unsigned)c * 2048;

    ushort4_t pks[16];
    float rsum = 0.f;

    // QK^T: per t, A-operand = K rows (= attention cols) n0+t*16+c, d-chunk g*8.
    // Output: lane holds score[q = c][kcol = n0 + t*16 + g*4 + r].
#pragma unroll
    for (int t = 0; t < 16; ++t) {
        const unsigned short* kp = kb + (size_t)(n0 + t * 16 + c) * 64 + g * 8;
        const f16x8 a0 = *(const f16x8*)(kp);
        const f16x8 a1 = *(const f16x8*)(kp + 32);
        f32x4 s = {0.f, 0.f, 0.f, 0.f};
        s = __builtin_amdgcn_mfma_f32_16x16x32_f16(a0, q0, s, 0, 0, 0);
        s = __builtin_amdgcn_mfma_f32_16x16x32_f16(a1, q1, s, 0, 0, 0);

        const float p0 = __expf(s[0] * 0.5f);
        const float p1 = __expf(s[1] * 0.5f);
        const float p2 = __expf(s[2] * 0.5f);
        const float p3 = __expf(s[3] * 0.5f);
        rsum += (p0 + p1) + (p2 + p3);

        ushort4_t pk;
        pk.x = f2bf(p0); pk.y = f2bf(p1); pk.z = f2bf(p2); pk.w = f2bf(p3);
        pks[t] = pk;
        // row = c, byte col = n0*2 + t*32 + g*8  (4 consecutive bf16 = 8B)
        *(ushort4_t*)((char*)P + ((prow + (unsigned)(n0 * 2 + t * 32 + g * 8)) ^ swzc)) = pk;
    }

    // row-sum for row c: reduce over the 4 lane-groups (lane-id bits 4,5)
    rsum += __shfl_xor(rsum, 16);
    rsum += __shfl_xor(rsum, 32);
    if (g == 0) rs_lds[w][c] = rsum;
    __syncthreads();                          // also covers P ds_writes
    if (tid < 16)
        inv_lds[tid] = 1.0f / (rs_lds[0][tid] + rs_lds[1][tid] + rs_lds[2][tid] + rs_lds[3][tid]);
    __syncthreads();

    // store-routing constants: lane l -> (row slot, chunk) for full-line stores
    const int rA = l >> 3, jj = l & 7;          // store A: rows 0-7
    const int rB = 8 + rA;                      // store B: rows 8-15
    const int slA = ((jj & 3) << 4) | rA;       // source lane (g=jj&3, c=row)
    const int slB = ((jj & 3) << 4) | rB;
    const float invA = inv_lds[rA];
    const float invB = inv_lds[rB];
    float* aoA = attn_out + ((size_t)bh << 20) + (size_t)(rb * 16 + rA) * 1024 + n0;
    float* aoB = attn_out + ((size_t)bh << 20) + (size_t)(rb * 16 + rB) * 1024 + n0;

    // PV with interleaved FULL-LINE NT attention stores.
    f32x4 pacc = {0.f, 0.f, 0.f, 0.f};
    const unsigned short* vb = vT + ((size_t)bh << 16) + (size_t)(w * 16 + c) * 1024;
#pragma unroll
    for (int ks = 0; ks < 32; ++ks) {
        const short8 a = *(const short8*)((char*)P + ((prow + (unsigned)(ks * 64 + g * 16)) ^ swzc));
        const short8 b = *(const short8*)(vb + ks * 32 + g * 8);
        pacc = __builtin_amdgcn_mfma_f32_16x16x32_bf16(a, b, pacc, 0, 0, 0);
        if (ks & 1) {
            const int p = ks >> 2;              // t-pair index 0..7
            const int t0 = 2 * p, t1 = t0 + 1;
            const bool isA = ((ks & 3) == 1);   // A at ks%4==1, B at ks%4==3
            const int sl = isA ? slA : slB;
            unsigned long long e0, e1;
            __builtin_memcpy(&e0, &pks[t0], 8);
            __builtin_memcpy(&e1, &pks[t1], 8);
            const unsigned long long ea = __shfl(e0, sl, 64);
            const unsigned long long eb = __shfl(e1, sl, 64);
            const unsigned long long sel = (jj < 4) ? ea : eb;
            const float inv2 = isA ? invA : invB;
            f32x4 o;
            o[0] = bf2f((unsigned short)(sel      )) * inv2;
            o[1] = bf2f((unsigned short)(sel >> 16)) * inv2;
            o[2] = bf2f((unsigned short)(sel >> 32)) * inv2;
            o[3] = bf2f((unsigned short)(sel >> 48)) * inv2;
            float* dst = (isA ? aoA : aoB) + p * 32 + jj * 4;
            __builtin_nontemporal_store(o, (f32x4*)dst);
        }
    }
    unsigned short* cb = ctx + ((size_t)bh << 16) + (size_t)(rb * 16) * 64 + w * 16 + c;
#pragma unroll
    for (int r = 0; r < 4; ++r) {
        const int row = g * 4 + r;
        cb[(size_t)row * 64] = f2bf(pacc[r] * inv_lds[row]);
    }
}

// =====================================================================
// BatchNorm over channels (deterministic two-level reduction)
// =====================================================================
__global__ void bn_stats(const float* __restrict__ x, float* __restrict__ psum, float* __restrict__ psq) {
    const int col = blockIdx.y * 256 + threadIdx.x;   // grid.y = 4
    const int r0 = blockIdx.x * 128;                  // grid.x = 64
    float s = 0.f, q = 0.f;
#pragma unroll 4
    for (int r = 0; r < 128; ++r) {
        const float v = x[(size_t)(r0 + r) * 1024 + col];
        s += v; q += v * v;
    }
    psum[blockIdx.x * 1024 + col] = s;
    psq [blockIdx.x * 1024 + col] = q;
}

__global__ void bn_final(const float* __restrict__ psum, const float* __restrict__ psq,
                         const float* __restrict__ gamma, const float* __restrict__ beta,
                         float* __restrict__ ab) {
    const int cidx = threadIdx.x;   // 1024 threads
    float s = 0.f, q = 0.f;
#pragma unroll 8
    for (int i = 0; i < 64; ++i) { s += psum[i * 1024 + cidx]; q += psq[i * 1024 + cidx]; }
    const float mean = s * (1.0f / 8192.0f);
    const float var  = q * (1.0f / 8192.0f) - mean * mean;
    const float a = gamma[cidx] * rsqrtf(var + 1e-5f);
    ab[cidx]        = a;
    ab[1024 + cidx] = beta[cidx] - mean * a;
}

__global__ void bn_apply(const float4* __restrict__ x4, const float* __restrict__ ab, float4* __restrict__ o4) {
    const int n4 = 2 * 1024 * 1024;
    for (int i = blockIdx.x * blockDim.x + threadIdx.x; i < n4; i += gridDim.x * blockDim.x) {
        const float4 v = x4[i];
        const int c0 = (i & 255) << 2;
        float4 r;
        r.x = v.x * ab[c0 + 0] + ab[1024 + c0 + 0];
        r.y = v.y * ab[c0 + 1] + ab[1024 + c0 + 1];
        r.z = v.z * ab[c0 + 2] + ab[1024 + c0 + 2];
        r.w = v.w * ab[c0 + 3] + ab[1024 + c0 + 3];
        o4[i] = r;
    }
}

// =====================================================================
// launch
// =====================================================================
extern "C" void kernel_launch(void* const* d_in, const int* in_sizes, int n_in,
                              void* d_out, int out_size, void* d_ws, size_t ws_size,
                              hipStream_t stream) {
    (void)in_sizes; (void)n_in; (void)out_size; (void)ws_size;

    const float* key   = (const float*)d_in[0];
    const float* value = (const float*)d_in[1];
    const float* query = (const float*)d_in[2];
    const float* Wk = (const float*)d_in[3];
    const float* bk = (const float*)d_in[4];
    const float* Wv = (const float*)d_in[5];
    const float* bv = (const float*)d_in[6];
    const float* Wq = (const float*)d_in[7];
    const float* bq = (const float*)d_in[8];
    const float* Wf = (const float*)d_in[9];
    const float* bff = (const float*)d_in[10];
    const float* gamma = (const float*)d_in[11];
    const float* beta  = (const float*)d_in[12];

    char* ws = (char*)d_ws;
    const size_t MB = 1u << 20;
    unsigned short* key16   = (unsigned short*)(ws + 0);        // dead after GEMM-k -> ctx
    unsigned short* ctx     = (unsigned short*)(ws + 0);
    unsigned short* query16 = (unsigned short*)(ws + 16 * MB);
    unsigned short* value16 = (unsigned short*)(ws + 32 * MB);
    float*          xbuf    = (float*)(ws + 16 * MB);           // 32 MB
    unsigned short* WkT = (unsigned short*)(ws + 48 * MB);
    unsigned short* WqT = (unsigned short*)(ws + 50 * MB);
    unsigned short* WvT = (unsigned short*)(ws + 52 * MB);
    unsigned short* WfT = (unsigned short*)(ws + 54 * MB);
    unsigned short* kbuf = (unsigned short*)(ws + 56 * MB);
    unsigned short* qbuf = (unsigned short*)(ws + 72 * MB);
    unsigned short* vbuf = (unsigned short*)(ws + 88 * MB);
    float* psum = (float*)(ws + 88 * MB);
    float* psq  = (float*)(ws + 88 * MB + 256 * 1024);
    float* ab   = (float*)(ws + 88 * MB + 512 * 1024);
    unsigned short* vTbuf = (unsigned short*)(ws + 104 * MB);

    float* out0 = (float*)d_out;            // [8M]  normalized output
    float* attn = out0 + 8388608;           // [128M] attention

    const int n4big = 2 * 1024 * 1024;

    // 1) input conversions (single batched launch)
    cvt3_f32_2b<<<dim3(1024, 3), 256, 0, stream>>>(
        (const float4*)key, (const float4*)query, (const float4*)value,
        (ushort4_t*)key16, (ushort4_t*)query16, (ushort4_t*)value16, n4big);

    // 2) weight transposes (single batched launch)
    dim3 tb(32, 8);
    transpose_cvt4<<<dim3(32, 32, 4), tb, 0, stream>>>(Wk, Wq, Wv, Wf, WkT, WqT, WvT, WfT);

    // 3) QKV projections (M=8192, N=1024, K=1024), f16 for q/k, bf16 for v
    gemm_bt<1, 0><<<512, 256, 0, stream>>>(key16,   WkT, bk, kbuf, nullptr, nullptr, 8192, 1024, 1024, 8);
    gemm_bt<1, 0><<<512, 256, 0, stream>>>(query16, WqT, bq, qbuf, nullptr, nullptr, 8192, 1024, 1024, 8);
    gemm_bt<0, 0><<<512, 256, 0, stream>>>(value16, WvT, bv, vbuf, nullptr, nullptr, 8192, 1024, 1024, 8);

    // 4) v -> vT per head-batch
    transpose_v<<<dim3(2, 32, 128), tb, 0, stream>>>(vbuf, vTbuf);

    // 5) attention (writes attention matrix + ctx), XCD-chunked 1-D grid
    attn_kernel<<<8192, 256, 0, stream>>>(qbuf, kbuf, vTbuf, attn, ctx);

    // 6) output projection + residual -> xbuf (f32)
    gemm_bt<0, 1><<<512, 256, 0, stream>>>(ctx, WfT, bff, nullptr, query, xbuf, 8192, 1024, 1024, 8);

    // 7) BatchNorm (deterministic)
    bn_stats<<<dim3(64, 4), 256, 0, stream>>>(xbuf, psum, psq);
    bn_final<<<1, 1024, 0, stream>>>(psum, psq, gamma, beta, ab);
    bn_apply<<<2048, 256, 0, stream>>>((const float4*)xbuf, ab, (float4*)out0);
}

// Round 17
// 402.824 us; speedup vs baseline: 1.2671x; 1.0575x over previous
//
#include <hip/hip_runtime.h>
#include <hip/hip_bf16.h>
#include <stdint.h>

// ---------- types ----------
typedef __attribute__((ext_vector_type(8))) short     short8;   // 8 bf16 (raw bits)
typedef __attribute__((ext_vector_type(8))) _Float16  f16x8;    // 8 fp16
typedef __attribute__((ext_vector_type(4))) float     f32x4;
typedef __attribute__((ext_vector_type(4))) unsigned short ushort4_t;

// ---------- scalar conversion helpers ----------
__device__ inline unsigned short f2bf(float f) {
    unsigned u = __float_as_uint(f);
    u += 0x7fffu + ((u >> 16) & 1u);          // RNE
    return (unsigned short)(u >> 16);
}
__device__ inline float bf2f(unsigned short h) {
    return __uint_as_float(((unsigned)h) << 16);
}
__device__ inline unsigned short f2h(float f) {
    _Float16 h = (_Float16)f;
    unsigned short r;
    __builtin_memcpy(&r, &h, 2);
    return r;
}

// ---------- async global->LDS (width 16) ----------
__device__ inline void gload16(const void* g, void* lds) {
    unsigned loff = (unsigned)(uintptr_t)lds;
    loff = __builtin_amdgcn_readfirstlane(loff);
    auto l = (__attribute__((address_space(3))) unsigned int*)(uintptr_t)loff;
    auto p = (const __attribute__((address_space(1))) unsigned int*)(uintptr_t)g;
    __builtin_amdgcn_global_load_lds(p, l, 16, 0, 0);
}

// =====================================================================
// Batched elementwise f32 -> 2-byte: y=0 key->f16, y=1 query->f16, y=2 value->bf16
// =====================================================================
__global__ void cvt3_f32_2b(const float4* __restrict__ k, const float4* __restrict__ q,
                            const float4* __restrict__ v,
                            ushort4_t* __restrict__ k16, ushort4_t* __restrict__ q16,
                            ushort4_t* __restrict__ v16, int n4) {
    const int which = blockIdx.y;
    const float4* in  = which == 0 ? k   : which == 1 ? q   : v;
    ushort4_t*    out = which == 0 ? k16 : which == 1 ? q16 : v16;
    const bool tof16 = (which < 2);
    for (int i = blockIdx.x * blockDim.x + threadIdx.x; i < n4; i += gridDim.x * blockDim.x) {
        float4 vv = in[i];
        ushort4_t r;
        if (tof16) { r.x = f2h(vv.x);  r.y = f2h(vv.y);  r.z = f2h(vv.z);  r.w = f2h(vv.w); }
        else       { r.x = f2bf(vv.x); r.y = f2bf(vv.y); r.z = f2bf(vv.z); r.w = f2bf(vv.w); }
        out[i] = r;
    }
}

// =====================================================================
// Batched weight transpose + convert: 4 weights in one launch.
// blockIdx.z: 0=Wk(f16) 1=Wq(f16) 2=Wv(bf16) 3=Wf(bf16)
// =====================================================================
__global__ void transpose_cvt4(const float* __restrict__ Wk, const float* __restrict__ Wq,
                               const float* __restrict__ Wv, const float* __restrict__ Wf,
                               unsigned short* __restrict__ WkT, unsigned short* __restrict__ WqT,
                               unsigned short* __restrict__ WvT, unsigned short* __restrict__ WfT) {
    const int which = blockIdx.z;
    const float* W = which == 0 ? Wk : which == 1 ? Wq : which == 2 ? Wv : Wf;
    unsigned short* WT = which == 0 ? WkT : which == 1 ? WqT : which == 2 ? WvT : WfT;
    const bool tof16 = (which < 2);
    const int dim = 1024;

    __shared__ float t[32][33];
    const int bx = blockIdx.x * 32, by = blockIdx.y * 32;   // bx: n, by: k
    const int tx = threadIdx.x, ty = threadIdx.y;
#pragma unroll
    for (int i = 0; i < 4; ++i)
        t[ty + 8 * i][tx] = W[(size_t)(by + ty + 8 * i) * dim + bx + tx];
    __syncthreads();
#pragma unroll
    for (int i = 0; i < 4; ++i) {
        float v = t[tx][ty + 8 * i];
        WT[(size_t)(bx + ty + 8 * i) * dim + by + tx] = tof16 ? f2h(v) : f2bf(v);
    }
}

// =====================================================================
// v [128][1024][64] bf16 -> vT [128][64][1024] bf16
// =====================================================================
__global__ void transpose_v(const unsigned short* __restrict__ v, unsigned short* __restrict__ vT) {
    const int bh = blockIdx.z, d0 = blockIdx.x * 32, s0 = blockIdx.y * 32;
    __shared__ unsigned short t[32][33];
    const int tx = threadIdx.x, ty = threadIdx.y;
    const size_t base = (size_t)bh << 16;
#pragma unroll
    for (int i = 0; i < 4; ++i)
        t[ty + 8 * i][tx] = v[base + (size_t)(s0 + ty + 8 * i) * 64 + d0 + tx];
    __syncthreads();
#pragma unroll
    for (int i = 0; i < 4; ++i)
        vT[base + (size_t)(d0 + ty + 8 * i) * 1024 + s0 + tx] = t[tx][ty + 8 * i];
}

// =====================================================================
// Merged QKV GEMM: one launch, blockIdx.y selects {k(f16), q(f16), v(bf16)}.
// BK=64 2-phase double-buffer, counted vmcnt(8), raw barriers (round 15).
// M=8192, N=1024, K=1024, 128x128 tile, 4 waves.
// =====================================================================
__global__ __launch_bounds__(256, 2) void qkv_gemm(
    const unsigned short* __restrict__ k16, const unsigned short* __restrict__ q16,
    const unsigned short* __restrict__ v16,
    const unsigned short* __restrict__ WkT, const unsigned short* __restrict__ WqT,
    const unsigned short* __restrict__ WvT,
    const float* __restrict__ bk, const float* __restrict__ bq, const float* __restrict__ bv,
    unsigned short* __restrict__ kout, unsigned short* __restrict__ qout,
    unsigned short* __restrict__ vout)
{
    const int which = blockIdx.y;
    const unsigned short* A   = which == 0 ? k16 : which == 1 ? q16 : v16;
    const unsigned short* Bt  = which == 0 ? WkT : which == 1 ? WqT : WvT;
    const float* bias         = which == 0 ? bk  : which == 1 ? bq  : bv;
    unsigned short* C2b       = which == 0 ? kout : which == 1 ? qout : vout;
    const bool f16in = (which < 2);
    const int N = 1024, K = 1024, nbx = 8;

    const int bid = blockIdx.x;
    const int cpx = gridDim.x >> 3;
    const int swz = (bid & 7) * cpx + (bid >> 3);
    const int bm = swz / nbx, bn = swz % nbx;
    const int m0 = bm * 128, n0 = bn * 128;

    const int tid = threadIdx.x;
    const int w = tid >> 6, l = tid & 63, g = l >> 4, c = l & 15;
    const int wr = w >> 1, wc = w & 1;

    __shared__ unsigned short As[2][8192];   // 2 x [128][64]
    __shared__ unsigned short Bs[2][8192];

    f32x4 acc[4][4] = {};

    const int srow = tid >> 3, scol = (tid & 7) * 8;
    const unsigned short* ApS = A  + (size_t)(m0 + srow) * K + scol;
    const unsigned short* BpS = Bt + (size_t)(n0 + srow) * K + scol;

    const int NT = K >> 6;

#define STAGE_GEMM(bufi, koff)                                                \
    do {                                                                      \
        _Pragma("unroll")                                                     \
        for (int i = 0; i < 4; ++i) {                                         \
            gload16(ApS + (size_t)i * 32 * K + (koff), &As[bufi][(i * 256 + tid - l) * 8]); \
            gload16(BpS + (size_t)i * 32 * K + (koff), &Bs[bufi][(i * 256 + tid - l) * 8]); \
        }                                                                     \
    } while (0)

#define COMPUTE_GEMM(bufi)                                                         \
    do {                                                                           \
        _Pragma("unroll")                                                          \
        for (int kk = 0; kk < 2; ++kk) {                                           \
            if (f16in) {                                                           \
                f16x8 a[4], b[4];                                                  \
                _Pragma("unroll")                                                  \
                for (int mt = 0; mt < 4; ++mt)                                     \
                    a[mt] = *(const f16x8*)&As[bufi][(wr * 64 + mt * 16 + c) * 64 + kk * 32 + g * 8]; \
                _Pragma("unroll")                                                  \
                for (int nt = 0; nt < 4; ++nt)                                     \
                    b[nt] = *(const f16x8*)&Bs[bufi][(wc * 64 + nt * 16 + c) * 64 + kk * 32 + g * 8]; \
                _Pragma("unroll")                                                  \
                for (int mt = 0; mt < 4; ++mt)                                     \
                    _Pragma("unroll")                                              \
                    for (int nt = 0; nt < 4; ++nt)                                 \
                        acc[mt][nt] = __builtin_amdgcn_mfma_f32_16x16x32_f16(a[mt], b[nt], acc[mt][nt], 0, 0, 0); \
            } else {                                                               \
                short8 a[4], b[4];                                                 \
                _Pragma("unroll")                                                  \
                for (int mt = 0; mt < 4; ++mt)                                     \
                    a[mt] = *(const short8*)&As[bufi][(wr * 64 + mt * 16 + c) * 64 + kk * 32 + g * 8]; \
                _Pragma("unroll")                                                  \
                for (int nt = 0; nt < 4; ++nt)                                     \
                    b[nt] = *(const short8*)&Bs[bufi][(wc * 64 + nt * 16 + c) * 64 + kk * 32 + g * 8]; \
                _Pragma("unroll")                                                  \
                for (int mt = 0; mt < 4; ++mt)                                     \
                    _Pragma("unroll")                                              \
                    for (int nt = 0; nt < 4; ++nt)                                 \
                        acc[mt][nt] = __builtin_amdgcn_mfma_f32_16x16x32_bf16(a[mt], b[nt], acc[mt][nt], 0, 0, 0); \
            }                                                                      \
        }                                                                          \
    } while (0)

    STAGE_GEMM(0, 0);

#pragma unroll 2
    for (int kt = 0; kt < NT - 1; ++kt) {
        const int cur = kt & 1;
        STAGE_GEMM(cur ^ 1, (kt + 1) * 64);
        asm volatile("s_waitcnt vmcnt(8)" ::: "memory");
        __builtin_amdgcn_s_barrier();
        __builtin_amdgcn_sched_barrier(0);
        COMPUTE_GEMM(cur);
        __builtin_amdgcn_sched_barrier(0);
        __builtin_amdgcn_s_barrier();
    }
    asm volatile("s_waitcnt vmcnt(0)" ::: "memory");
    __builtin_amdgcn_s_barrier();
    __builtin_amdgcn_sched_barrier(0);
    COMPUTE_GEMM((NT - 1) & 1);

#undef STAGE_GEMM
#undef COMPUTE_GEMM

#pragma unroll
    for (int nt = 0; nt < 4; ++nt) {
        const int col = n0 + wc * 64 + nt * 16 + c;
        const float bs = bias[col];
#pragma unroll
        for (int mt = 0; mt < 4; ++mt) {
            const int row0 = m0 + wr * 64 + mt * 16 + g * 4;
#pragma unroll
            for (int r = 0; r < 4; ++r) {
                const float x = acc[mt][nt][r] + bs;
                const size_t idx = (size_t)(row0 + r) * N + col;
                C2b[idx] = f16in ? f2h(x) : f2bf(x);
            }
        }
    }
}

// =====================================================================
// Output GEMM (bf16 in, f32 out = acc + bias + resid) with FUSED BN
// column partial-stats: psum/psq[bm][col] (deterministic; replaces
// bn_stats). Same BK=64 2-phase structure.
// =====================================================================
__global__ __launch_bounds__(256, 2) void gemm_out(
    const unsigned short* __restrict__ A,
    const unsigned short* __restrict__ Bt,
    const float* __restrict__ bias,
    const float* __restrict__ resid,
    float* __restrict__ Cf,
    float* __restrict__ psum,
    float* __restrict__ psq)
{
    const int N = 1024, K = 1024, nbx = 8;
    const int bid = blockIdx.x;
    const int cpx = gridDim.x >> 3;
    const int swz = (bid & 7) * cpx + (bid >> 3);
    const int bm = swz / nbx, bn = swz % nbx;
    const int m0 = bm * 128, n0 = bn * 128;

    const int tid = threadIdx.x;
    const int w = tid >> 6, l = tid & 63, g = l >> 4, c = l & 15;
    const int wr = w >> 1, wc = w & 1;

    __shared__ unsigned short As[2][8192];
    __shared__ unsigned short Bs[2][8192];
    __shared__ float sred[2][2][4][16][2];   // [wr][wc][nt][c][s|q], 4 KB

    f32x4 acc[4][4] = {};

    const int srow = tid >> 3, scol = (tid & 7) * 8;
    const unsigned short* ApS = A  + (size_t)(m0 + srow) * K + scol;
    const unsigned short* BpS = Bt + (size_t)(n0 + srow) * K + scol;

    const int NT = K >> 6;

#define STAGE_GEMM(bufi, koff)                                                \
    do {                                                                      \
        _Pragma("unroll")                                                     \
        for (int i = 0; i < 4; ++i) {                                         \
            gload16(ApS + (size_t)i * 32 * K + (koff), &As[bufi][(i * 256 + tid - l) * 8]); \
            gload16(BpS + (size_t)i * 32 * K + (koff), &Bs[bufi][(i * 256 + tid - l) * 8]); \
        }                                                                     \
    } while (0)

#define COMPUTE_GEMM(bufi)                                                         \
    do {                                                                           \
        _Pragma("unroll")                                                          \
        for (int kk = 0; kk < 2; ++kk) {                                           \
            short8 a[4], b[4];                                                     \
            _Pragma("unroll")                                                      \
            for (int mt = 0; mt < 4; ++mt)                                         \
                a[mt] = *(const short8*)&As[bufi][(wr * 64 + mt * 16 + c) * 64 + kk * 32 + g * 8]; \
            _Pragma("unroll")                                                      \
            for (int nt = 0; nt < 4; ++nt)                                         \
                b[nt] = *(const short8*)&Bs[bufi][(wc * 64 + nt * 16 + c) * 64 + kk * 32 + g * 8]; \
            _Pragma("unroll")                                                      \
            for (int mt = 0; mt < 4; ++mt)                                         \
                _Pragma("unroll")                                                  \
                for (int nt = 0; nt < 4; ++nt)                                     \
                    acc[mt][nt] = __builtin_amdgcn_mfma_f32_16x16x32_bf16(a[mt], b[nt], acc[mt][nt], 0, 0, 0); \
        }                                                                          \
    } while (0)

    STAGE_GEMM(0, 0);

#pragma unroll 2
    for (int kt = 0; kt < NT - 1; ++kt) {
        const int cur = kt & 1;
        STAGE_GEMM(cur ^ 1, (kt + 1) * 64);
        asm volatile("s_waitcnt vmcnt(8)" ::: "memory");
        __builtin_amdgcn_s_barrier();
        __builtin_amdgcn_sched_barrier(0);
        COMPUTE_GEMM(cur);
        __builtin_amdgcn_sched_barrier(0);
        __builtin_amdgcn_s_barrier();
    }
    asm volatile("s_waitcnt vmcnt(0)" ::: "memory");
    __builtin_amdgcn_s_barrier();
    __builtin_amdgcn_sched_barrier(0);
    COMPUTE_GEMM((NT - 1) & 1);

#undef STAGE_GEMM
#undef COMPUTE_GEMM

    // epilogue: x = acc + bias + resid -> Cf; accumulate column stats
    float s_nt[4] = {0.f, 0.f, 0.f, 0.f};
    float q_nt[4] = {0.f, 0.f, 0.f, 0.f};
#pragma unroll
    for (int nt = 0; nt < 4; ++nt) {
        const int col = n0 + wc * 64 + nt * 16 + c;
        const float bs = bias[col];
#pragma unroll
        for (int mt = 0; mt < 4; ++mt) {
            const int row0 = m0 + wr * 64 + mt * 16 + g * 4;
#pragma unroll
            for (int r = 0; r < 4; ++r) {
                const size_t idx = (size_t)(row0 + r) * N + col;
                const float xv = acc[mt][nt][r] + bs + resid[idx];
                Cf[idx] = xv;
                s_nt[nt] += xv;
                q_nt[nt] += xv * xv;
            }
        }
    }
    // reduce over the 4 g-groups (lane bits 4,5); rows covered: this wave's 64
#pragma unroll
    for (int nt = 0; nt < 4; ++nt) {
        s_nt[nt] += __shfl_xor(s_nt[nt], 16);
        s_nt[nt] += __shfl_xor(s_nt[nt], 32);
        q_nt[nt] += __shfl_xor(q_nt[nt], 16);
        q_nt[nt] += __shfl_xor(q_nt[nt], 32);
    }
    if (g == 0) {
#pragma unroll
        for (int nt = 0; nt < 4; ++nt) {
            sred[wr][wc][nt][c][0] = s_nt[nt];
            sred[wr][wc][nt][c][1] = q_nt[nt];
        }
    }
    __syncthreads();
    if (tid < 128) {
        const int wc2 = tid >> 6, nt2 = (tid >> 4) & 3, c2 = tid & 15;
        const float ss = sred[0][wc2][nt2][c2][0] + sred[1][wc2][nt2][c2][0];
        const float qq = sred[0][wc2][nt2][c2][1] + sred[1][wc2][nt2][c2][1];
        const int col = n0 + wc2 * 64 + nt2 * 16 + c2;
        psum[bm * 1024 + col] = ss;
        psq [bm * 1024 + col] = qq;
    }
}

// =====================================================================
// Attention v12 (round 14, best known): swapped QK^T, packed bf16
// pks[16], FULL-LINE NT stores via __shfl interleaved into PV,
// XCD-chunked decode. One block = (bh, 16 q-rows); grid = 8192.
// =====================================================================
__global__ __launch_bounds__(256, 4) void attn_kernel(
    const unsigned short* __restrict__ qf,   // f16  [128*1024*64]
    const unsigned short* __restrict__ kf,   // f16  [128*1024*64]
    const unsigned short* __restrict__ vT,   // bf16 [128][64][1024]
    float* __restrict__ attn_out,            // f32  [128][1024][1024]
    unsigned short* __restrict__ ctx)        // bf16 [128*1024*64]
{
    const int L = blockIdx.x;
    const int rb = (L >> 3) & 63;
    const int bh = ((L & 7) << 4) | (L >> 9);

    const int tid = threadIdx.x;
    const int w = tid >> 6, l = tid & 63, g = l >> 4, c = l & 15;
    const int n0 = w * 256;

    __shared__ unsigned short P[16 * 1024];  // 32 KB, XOR-swizzled by (row&7)<<4
    __shared__ float rs_lds[4][16];
    __shared__ float inv_lds[16];

    const unsigned short* qb = qf + ((size_t)bh << 16) + (size_t)(rb * 16 + c) * 64 + g * 8;
    const f16x8 q0 = *(const f16x8*)(qb);
    const f16x8 q1 = *(const f16x8*)(qb + 32);

    const unsigned short* kb = kf + ((size_t)bh << 16);
    const unsigned swzc = ((unsigned)(c & 7)) << 4;
    const unsigned prow = (unsigned)c * 2048;

    ushort4_t pks[16];
    float rsum = 0.f;

#pragma unroll
    for (int t = 0; t < 16; ++t) {
        const unsigned short* kp = kb + (size_t)(n0 + t * 16 + c) * 64 + g * 8;
        const f16x8 a0 = *(const f16x8*)(kp);
        const f16x8 a1 = *(const f16x8*)(kp + 32);
        f32x4 s = {0.f, 0.f, 0.f, 0.f};
        s = __builtin_amdgcn_mfma_f32_16x16x32_f16(a0, q0, s, 0, 0, 0);
        s = __builtin_amdgcn_mfma_f32_16x16x32_f16(a1, q1, s, 0, 0, 0);

        const float p0 = __expf(s[0] * 0.5f);
        const float p1 = __expf(s[1] * 0.5f);
        const float p2 = __expf(s[2] * 0.5f);
        const float p3 = __expf(s[3] * 0.5f);
        rsum += (p0 + p1) + (p2 + p3);

        ushort4_t pk;
        pk.x = f2bf(p0); pk.y = f2bf(p1); pk.z = f2bf(p2); pk.w = f2bf(p3);
        pks[t] = pk;
        *(ushort4_t*)((char*)P + ((prow + (unsigned)(n0 * 2 + t * 32 + g * 8)) ^ swzc)) = pk;
    }

    rsum += __shfl_xor(rsum, 16);
    rsum += __shfl_xor(rsum, 32);
    if (g == 0) rs_lds[w][c] = rsum;
    __syncthreads();
    if (tid < 16)
        inv_lds[tid] = 1.0f / (rs_lds[0][tid] + rs_lds[1][tid] + rs_lds[2][tid] + rs_lds[3][tid]);
    __syncthreads();

    const int rA = l >> 3, jj = l & 7;
    const int rB = 8 + rA;
    const int slA = ((jj & 3) << 4) | rA;
    const int slB = ((jj & 3) << 4) | rB;
    const float invA = inv_lds[rA];
    const float invB = inv_lds[rB];
    float* aoA = attn_out + ((size_t)bh << 20) + (size_t)(rb * 16 + rA) * 1024 + n0;
    float* aoB = attn_out + ((size_t)bh << 20) + (size_t)(rb * 16 + rB) * 1024 + n0;

    f32x4 pacc = {0.f, 0.f, 0.f, 0.f};
    const unsigned short* vb = vT + ((size_t)bh << 16) + (size_t)(w * 16 + c) * 1024;
#pragma unroll
    for (int ks = 0; ks < 32; ++ks) {
        const short8 a = *(const short8*)((char*)P + ((prow + (unsigned)(ks * 64 + g * 16)) ^ swzc));
        const short8 b = *(const short8*)(vb + ks * 32 + g * 8);
        pacc = __builtin_amdgcn_mfma_f32_16x16x32_bf16(a, b, pacc, 0, 0, 0);
        if (ks & 1) {
            const int p = ks >> 2;
            const int t0 = 2 * p, t1 = t0 + 1;
            const bool isA = ((ks & 3) == 1);
            const int sl = isA ? slA : slB;
            unsigned long long e0, e1;
            __builtin_memcpy(&e0, &pks[t0], 8);
            __builtin_memcpy(&e1, &pks[t1], 8);
            const unsigned long long ea = __shfl(e0, sl, 64);
            const unsigned long long eb = __shfl(e1, sl, 64);
            const unsigned long long sel = (jj < 4) ? ea : eb;
            const float inv2 = isA ? invA : invB;
            f32x4 o;
            o[0] = bf2f((unsigned short)(sel      )) * inv2;
            o[1] = bf2f((unsigned short)(sel >> 16)) * inv2;
            o[2] = bf2f((unsigned short)(sel >> 32)) * inv2;
            o[3] = bf2f((unsigned short)(sel >> 48)) * inv2;
            float* dst = (isA ? aoA : aoB) + p * 32 + jj * 4;
            __builtin_nontemporal_store(o, (f32x4*)dst);
        }
    }
    unsigned short* cb = ctx + ((size_t)bh << 16) + (size_t)(rb * 16) * 64 + w * 16 + c;
#pragma unroll
    for (int r = 0; r < 4; ++r) {
        const int row = g * 4 + r;
        cb[(size_t)row * 64] = f2bf(pacc[r] * inv_lds[row]);
    }
}

// =====================================================================
// BatchNorm finalize + apply (stats produced by gemm_out epilogue)
// =====================================================================
__global__ void bn_final(const float* __restrict__ psum, const float* __restrict__ psq,
                         const float* __restrict__ gamma, const float* __restrict__ beta,
                         float* __restrict__ ab) {
    const int cidx = threadIdx.x;   // 1024 threads
    float s = 0.f, q = 0.f;
#pragma unroll 8
    for (int i = 0; i < 64; ++i) { s += psum[i * 1024 + cidx]; q += psq[i * 1024 + cidx]; }
    const float mean = s * (1.0f / 8192.0f);
    const float var  = q * (1.0f / 8192.0f) - mean * mean;
    const float a = gamma[cidx] * rsqrtf(var + 1e-5f);
    ab[cidx]        = a;
    ab[1024 + cidx] = beta[cidx] - mean * a;
}

__global__ void bn_apply(const float4* __restrict__ x4, const float* __restrict__ ab, float4* __restrict__ o4) {
    const int n4 = 2 * 1024 * 1024;
    for (int i = blockIdx.x * blockDim.x + threadIdx.x; i < n4; i += gridDim.x * blockDim.x) {
        const float4 v = x4[i];
        const int c0 = (i & 255) << 2;
        float4 r;
        r.x = v.x * ab[c0 + 0] + ab[1024 + c0 + 0];
        r.y = v.y * ab[c0 + 1] + ab[1024 + c0 + 1];
        r.z = v.z * ab[c0 + 2] + ab[1024 + c0 + 2];
        r.w = v.w * ab[c0 + 3] + ab[1024 + c0 + 3];
        o4[i] = r;
    }
}

// =====================================================================
// launch
// =====================================================================
extern "C" void kernel_launch(void* const* d_in, const int* in_sizes, int n_in,
                              void* d_out, int out_size, void* d_ws, size_t ws_size,
                              hipStream_t stream) {
    (void)in_sizes; (void)n_in; (void)out_size; (void)ws_size;

    const float* key   = (const float*)d_in[0];
    const float* value = (const float*)d_in[1];
    const float* query = (const float*)d_in[2];
    const float* Wk = (const float*)d_in[3];
    const float* bk = (const float*)d_in[4];
    const float* Wv = (const float*)d_in[5];
    const float* bv = (const float*)d_in[6];
    const float* Wq = (const float*)d_in[7];
    const float* bq = (const float*)d_in[8];
    const float* Wf = (const float*)d_in[9];
    const float* bff = (const float*)d_in[10];
    const float* gamma = (const float*)d_in[11];
    const float* beta  = (const float*)d_in[12];

    char* ws = (char*)d_ws;
    const size_t MB = 1u << 20;
    unsigned short* key16   = (unsigned short*)(ws + 0);        // dead after GEMM-k -> ctx
    unsigned short* ctx     = (unsigned short*)(ws + 0);
    unsigned short* query16 = (unsigned short*)(ws + 16 * MB);
    unsigned short* value16 = (unsigned short*)(ws + 32 * MB);
    float*          xbuf    = (float*)(ws + 16 * MB);           // 32 MB
    unsigned short* WkT = (unsigned short*)(ws + 48 * MB);
    unsigned short* WqT = (unsigned short*)(ws + 50 * MB);
    unsigned short* WvT = (unsigned short*)(ws + 52 * MB);
    unsigned short* WfT = (unsigned short*)(ws + 54 * MB);
    unsigned short* kbuf = (unsigned short*)(ws + 56 * MB);
    unsigned short* qbuf = (unsigned short*)(ws + 72 * MB);
    unsigned short* vbuf = (unsigned short*)(ws + 88 * MB);
    float* psum = (float*)(ws + 88 * MB);
    float* psq  = (float*)(ws + 88 * MB + 256 * 1024);
    float* ab   = (float*)(ws + 88 * MB + 512 * 1024);
    unsigned short* vTbuf = (unsigned short*)(ws + 104 * MB);

    float* out0 = (float*)d_out;            // [8M]  normalized output
    float* attn = out0 + 8388608;           // [128M] attention

    const int n4big = 2 * 1024 * 1024;

    // 1) input conversions (single batched launch)
    cvt3_f32_2b<<<dim3(1024, 3), 256, 0, stream>>>(
        (const float4*)key, (const float4*)query, (const float4*)value,
        (ushort4_t*)key16, (ushort4_t*)query16, (ushort4_t*)value16, n4big);

    // 2) weight transposes (single batched launch)
    dim3 tb(32, 8);
    transpose_cvt4<<<dim3(32, 32, 4), tb, 0, stream>>>(Wk, Wq, Wv, Wf, WkT, WqT, WvT, WfT);

    // 3) QKV projections, merged into ONE launch (y selects k/q/v)
    qkv_gemm<<<dim3(512, 3), 256, 0, stream>>>(
        key16, query16, value16, WkT, WqT, WvT, bk, bq, bv, kbuf, qbuf, vbuf);

    // 4) v -> vT per head-batch
    transpose_v<<<dim3(2, 32, 128), tb, 0, stream>>>(vbuf, vTbuf);

    // 5) attention (writes attention matrix + ctx), XCD-chunked 1-D grid
    attn_kernel<<<8192, 256, 0, stream>>>(qbuf, kbuf, vTbuf, attn, ctx);

    // 6) output projection + residual -> xbuf, with fused BN column stats
    gemm_out<<<512, 256, 0, stream>>>(ctx, WfT, bff, query, xbuf, psum, psq);

    // 7) BatchNorm finalize + apply
    bn_final<<<1, 1024, 0, stream>>>(psum, psq, gamma, beta, ab);
    bn_apply<<<2048, 256, 0, stream>>>((const float4*)xbuf, ab, (float4*)out0);
}